// Round 3
// baseline (748.091 us; speedup 1.0000x reference)
//
#include <hip/hip_runtime.h>
#include <hip/hip_bf16.h>
#include <stdint.h>

#define N_NODES 10000
#define N_EDGES 160000

typedef unsigned short u16;
typedef unsigned int u32;

__device__ __forceinline__ float bf2f(u16 v){ return __uint_as_float(((u32)v) << 16); }
__device__ __forceinline__ float lo16(u32 u){ return __uint_as_float(u << 16); }
__device__ __forceinline__ float hi16(u32 u){ return __uint_as_float(u & 0xffff0000u); }
__device__ __forceinline__ u16 f2bf(float f){
    u32 u = __float_as_uint(f);
    u32 r = (u + 0x7fffu + ((u >> 16) & 1u)) >> 16;
    return (u16)r;
}
__device__ __forceinline__ u32 pack2(float a, float b){
    return (u32)f2bf(a) | ((u32)f2bf(b) << 16);
}

// ---------------- fp32 -> bf16 canonicalization ----------------
__global__ void k_convert_x(const float* __restrict__ src, u16* __restrict__ dst){
    int i = blockIdx.x * blockDim.x + threadIdx.x;
    if (i < N_NODES * 32 * 12) dst[i] = f2bf(src[i]);
}

struct SmallPtrs { const void* p[14]; };

// 14 weight/bias tensors packed into one contiguous bf16 buffer
__device__ __constant__ const int g_seg_off[15] = {
    0, 12288, 12416, 16512, 16576, 41152, 41280,
    65856, 65984, 70080, 70144, 94720, 94848, 104064, 104076
};

__global__ void k_convert_small(SmallPtrs ps, u16* __restrict__ dst){
    int i = blockIdx.x * blockDim.x + threadIdx.x;
    if (i >= 104076) return;
    int seg = 0, base = 0;
#pragma unroll
    for (int s = 0; s < 14; s++){
        if (i >= g_seg_off[s]){ seg = s; base = g_seg_off[s]; }
    }
    dst[i] = f2bf(((const float*)ps.p[seg])[i - base]);
}

// ---------------- graph prep ----------------
__global__ void k_graph_init(float* deg, int* cnt, int* cur){
    int i = blockIdx.x * blockDim.x + threadIdx.x;
    if (i < N_NODES){ deg[i] = 1.0f; cnt[i] = 0; cur[i] = 0; }
}

__global__ void k_graph_count(const int* __restrict__ ei, const float* __restrict__ ew,
                              float* deg, int* cnt){
    int e = blockIdx.x * blockDim.x + threadIdx.x;
    if (e < N_EDGES){
        int d = ei[N_EDGES + e];
        atomicAdd(&deg[d], ew[e]);
        atomicAdd(&cnt[d], 1);
    }
}

__global__ void k_scan(const int* __restrict__ cnt, int* __restrict__ off){
    __shared__ int tmp[1024];
    __shared__ int carry;
    int tid = threadIdx.x;
    if (tid == 0) carry = 0;
    __syncthreads();
    for (int base = 0; base < N_NODES; base += 1024){
        int i = base + tid;
        int v = (i < N_NODES) ? cnt[i] : 0;
        tmp[tid] = v;
        __syncthreads();
        for (int s = 1; s < 1024; s <<= 1){
            int t = (tid >= s) ? tmp[tid - s] : 0;
            __syncthreads();
            tmp[tid] += t;
            __syncthreads();
        }
        if (i < N_NODES) off[i] = carry + tmp[tid] - v;   // exclusive
        __syncthreads();
        if (tid == 0) carry += tmp[1023];
        __syncthreads();
    }
    if (tid == 0) off[N_NODES] = carry;
}

__global__ void k_dis(const float* __restrict__ deg, float* __restrict__ dis){
    int i = blockIdx.x * blockDim.x + threadIdx.x;
    if (i < N_NODES) dis[i] = rsqrtf(deg[i]);   // deg >= 1 always (self loop)
}

__global__ void k_scatter(const int* __restrict__ ei, const float* __restrict__ ew,
                          const float* __restrict__ dis, const int* __restrict__ off,
                          int* cur, int* __restrict__ esrc, float* __restrict__ enorm){
    int e = blockIdx.x * blockDim.x + threadIdx.x;
    if (e < N_EDGES){
        int s = ei[e];
        int d = ei[N_EDGES + e];
        float nw = dis[s] * ew[e] * dis[d];
        int p = off[d] + atomicAdd(&cur[d], 1);
        esrc[p] = s;
        enorm[p] = nw;
    }
}

// ---------------- gated temporal conv ----------------
// in: [N][CIN][12] bf16, w: [128][CIN][3] bf16, b: [128] bf16
// out[n][p][t] = P * sigmoid(Q), P=rows 0..63, Q=rows 64..127
template<int CIN_>
__launch_bounds__(256, 2)
__global__ void k_gconv(const u16* __restrict__ xin, const u16* __restrict__ wg,
                        const u16* __restrict__ bg, u16* __restrict__ out){
    __shared__ u16 wl[CIN_ * 3 * 128];     // [c][k][o]
    __shared__ u16 xs[8][CIN_][14];        // padded time axis: [0]=pad, [1..12]=x, [13]=pad
    int tid = threadIdx.x;

    // stage weights: global [o][c*3+k] -> lds [(c*3+k)*128 + o]
    for (int i = tid; i < CIN_ * 3 * 128; i += 256){
        int o = i / (CIN_ * 3);
        int r = i % (CIN_ * 3);
        wl[r * 128 + o] = wg[i];
    }
    // zero time pads
    for (int i = tid; i < 8 * CIN_; i += 256){
        int g = i / CIN_, c = i % CIN_;
        xs[g][c][0] = 0; xs[g][c][13] = 0;
    }
    int n0 = blockIdx.x * 8;
    // stage x (quads of 4 bf16)
    constexpr int QUADS = CIN_ * 3;        // (CIN*12)/4 per node
    for (int i = tid; i < 8 * QUADS; i += 256){
        int g = i / QUADS, r = i % QUADS;
        int c = r / 3, t4 = (r % 3) * 4;
        const u16* src = xin + ((size_t)(n0 + g) * CIN_ + c) * 12 + t4;
        u32 u0 = *(const u32*)src;
        u32 u1 = *(const u32*)(src + 2);
        xs[g][c][1 + t4 + 0] = (u16)(u0 & 0xffffu);
        xs[g][c][1 + t4 + 1] = (u16)(u0 >> 16);
        xs[g][c][1 + t4 + 2] = (u16)(u1 & 0xffffu);
        xs[g][c][1 + t4 + 3] = (u16)(u1 >> 16);
    }
    __syncthreads();

    int L = tid & 31;       // channel-pair owner
    int g = tid >> 5;       // node within group
    int n = n0 + g;
    int p0 = L * 2;

    float aP0[12], aP1[12], aQ0[12], aQ1[12];
#pragma unroll
    for (int t = 0; t < 12; t++){ aP0[t] = aP1[t] = aQ0[t] = aQ1[t] = 0.f; }

    for (int c = 0; c < CIN_; c++){
        float xv[14];
        const u32* xrow = (const u32*)&xs[g][c][0];   // 28B rows, 4B aligned
#pragma unroll
        for (int i = 0; i < 7; i++){ u32 u = xrow[i]; xv[2*i] = lo16(u); xv[2*i+1] = hi16(u); }
#pragma unroll
        for (int k = 0; k < 3; k++){
            const u16* wrow = &wl[(c * 3 + k) * 128];
            u32 uP = *(const u32*)&wrow[p0];
            u32 uQ = *(const u32*)&wrow[64 + p0];
            float wp0 = lo16(uP), wp1 = hi16(uP);
            float wq0 = lo16(uQ), wq1 = hi16(uQ);
#pragma unroll
            for (int t = 0; t < 12; t++){
                float xvv = xv[t + k];
                aP0[t] = fmaf(wp0, xvv, aP0[t]);
                aP1[t] = fmaf(wp1, xvv, aP1[t]);
                aQ0[t] = fmaf(wq0, xvv, aQ0[t]);
                aQ1[t] = fmaf(wq1, xvv, aQ1[t]);
            }
        }
    }

    float bp0 = bf2f(bg[p0]),      bp1 = bf2f(bg[p0 + 1]);
    float bq0 = bf2f(bg[64 + p0]), bq1 = bf2f(bg[64 + p0 + 1]);
    float h0[12], h1[12];
#pragma unroll
    for (int t = 0; t < 12; t++){
        float pv0 = aP0[t] + bp0, qv0 = aQ0[t] + bq0;
        float pv1 = aP1[t] + bp1, qv1 = aQ1[t] + bq1;
        h0[t] = pv0 / (1.f + __expf(-qv0));
        h1[t] = pv1 / (1.f + __expf(-qv1));
    }
    u32* o0p = (u32*)(out + ((size_t)n * 64 + p0) * 12);
    u32* o1p = (u32*)(out + ((size_t)n * 64 + p0 + 1) * 12);
#pragma unroll
    for (int i = 0; i < 6; i++){
        o0p[i] = pack2(h0[2*i], h0[2*i+1]);
        o1p[i] = pack2(h1[2*i], h1[2*i+1]);
    }
}

// ---------------- GCN aggregation: z[n] = dis[n]^2 * x[n] + sum_e norm_e * x[src_e] ----------------
__global__ void k_agg(const u16* __restrict__ x, u16* __restrict__ out,
                      const float* __restrict__ dis, const int* __restrict__ off,
                      const int* __restrict__ esrc, const float* __restrict__ enorm){
    int n = blockIdx.x;
    int v0 = threadIdx.x * 4;       // blockDim = 192, covers 768
    float d = dis[n];
    float sw = d * d;
    const u16* xr = x + (size_t)n * 768 + v0;
    u32 u0 = *(const u32*)xr;
    u32 u1 = *(const u32*)(xr + 2);
    float a0 = sw * lo16(u0), a1 = sw * hi16(u0);
    float a2 = sw * lo16(u1), a3 = sw * hi16(u1);
    int b = off[n], e = off[n + 1];
    for (int p = b; p < e; p++){
        int s = esrc[p];
        float w = enorm[p];
        const u16* q = x + (size_t)s * 768 + v0;
        u32 w0 = *(const u32*)q;
        u32 w1 = *(const u32*)(q + 2);
        a0 = fmaf(w, lo16(w0), a0); a1 = fmaf(w, hi16(w0), a1);
        a2 = fmaf(w, lo16(w1), a2); a3 = fmaf(w, hi16(w1), a3);
    }
    u16* o = out + (size_t)n * 768 + v0;
    *(u32*)o       = pack2(a0, a1);
    *(u32*)(o + 2) = pack2(a2, a3);
}

// ---------------- channel mix + bias + relu: out[n][o][t] = relu(sum_c z[n][c][t]*W[o][c] + b[o]) ----------------
__launch_bounds__(256, 2)
__global__ void k_mm_bias_relu(const u16* __restrict__ zin, const u16* __restrict__ Wg,
                               const u16* __restrict__ bg, u16* __restrict__ out){
    __shared__ u16 wl[64 * 64];        // [c][o]
    __shared__ float zs[8][64][12];    // fp32 staged input
    int tid = threadIdx.x;
    for (int i = tid; i < 64 * 64; i += 256){
        int o = i >> 6, c = i & 63;
        wl[c * 64 + o] = Wg[i];
    }
    int n0 = blockIdx.x * 8;
    for (int i = tid; i < 8 * 192; i += 256){
        int g = i / 192, r = i % 192;
        int c = r / 3, t4 = (r % 3) * 4;
        const u16* src = zin + ((size_t)(n0 + g) * 64 + c) * 12 + t4;
        u32 u0 = *(const u32*)src;
        u32 u1 = *(const u32*)(src + 2);
        zs[g][c][t4 + 0] = lo16(u0); zs[g][c][t4 + 1] = hi16(u0);
        zs[g][c][t4 + 2] = lo16(u1); zs[g][c][t4 + 3] = hi16(u1);
    }
    __syncthreads();

    int L = tid & 31, g = tid >> 5;
    int n = n0 + g;
    int o0 = 2 * L;
    float a0[12], a1[12];
#pragma unroll
    for (int t = 0; t < 12; t++){ a0[t] = a1[t] = 0.f; }
    for (int c = 0; c < 64; c++){
        u32 uw = *(const u32*)&wl[c * 64 + o0];
        float w0 = lo16(uw), w1 = hi16(uw);
        const float4* zr4 = (const float4*)&zs[g][c][0];   // 48B rows, 16B aligned
#pragma unroll
        for (int q = 0; q < 3; q++){
            float4 z4 = zr4[q];
            a0[4*q+0] = fmaf(w0, z4.x, a0[4*q+0]); a1[4*q+0] = fmaf(w1, z4.x, a1[4*q+0]);
            a0[4*q+1] = fmaf(w0, z4.y, a0[4*q+1]); a1[4*q+1] = fmaf(w1, z4.y, a1[4*q+1]);
            a0[4*q+2] = fmaf(w0, z4.z, a0[4*q+2]); a1[4*q+2] = fmaf(w1, z4.z, a1[4*q+2]);
            a0[4*q+3] = fmaf(w0, z4.w, a0[4*q+3]); a1[4*q+3] = fmaf(w1, z4.w, a1[4*q+3]);
        }
    }
    float b0 = bf2f(bg[o0]), b1 = bf2f(bg[o0 + 1]);
    u32* o0p = (u32*)(out + ((size_t)n * 64 + o0) * 12);
    u32* o1p = (u32*)(out + ((size_t)n * 64 + o0 + 1) * 12);
#pragma unroll
    for (int i = 0; i < 6; i++){
        float r00 = fmaxf(a0[2*i]   + b0, 0.f);
        float r01 = fmaxf(a0[2*i+1] + b0, 0.f);
        float r10 = fmaxf(a1[2*i]   + b1, 0.f);
        float r11 = fmaxf(a1[2*i+1] + b1, 0.f);
        o0p[i] = pack2(r00, r01);
        o1p[i] = pack2(r10, r11);
    }
}

// ---------------- final conv: out[n][o] = sum_{flat} h[n][flat] * fw[o][flat] + fb[o] ----------------
// OUTPUT IS FP32 (reference output dtype float32)
__launch_bounds__(256)
__global__ void k_final(const u16* __restrict__ h, const u16* __restrict__ fw,
                        const u16* __restrict__ fb, float* __restrict__ out){
    __shared__ u16 wsh[12 * 768];
    int tid = threadIdx.x;
    for (int i = tid; i < 12 * 768; i += 256) wsh[i] = fw[i];
    __syncthreads();
    int lane = tid & 63, wv = tid >> 6;
    int n = blockIdx.x * 4 + wv;
    float hv[12];
    const u16* hr = h + (size_t)n * 768;
#pragma unroll
    for (int j = 0; j < 12; j++) hv[j] = bf2f(hr[lane + 64 * j]);
    float acc[12];
#pragma unroll
    for (int o = 0; o < 12; o++){
        float a = 0.f;
#pragma unroll
        for (int j = 0; j < 12; j++) a = fmaf(hv[j], bf2f(wsh[o * 768 + lane + 64 * j]), a);
        acc[o] = a;
    }
#pragma unroll
    for (int s = 32; s >= 1; s >>= 1){
#pragma unroll
        for (int o = 0; o < 12; o++) acc[o] += __shfl_xor(acc[o], s, 64);
    }
    if (lane == 0){
#pragma unroll
        for (int o = 0; o < 12; o++) out[n * 12 + o] = acc[o] + bf2f(fb[o]);
    }
}

// ---------------- launch ----------------
static inline size_t align256(size_t x){ return (x + 255) & ~(size_t)255; }

extern "C" void kernel_launch(void* const* d_in, const int* in_sizes, int n_in,
                              void* d_out, int out_size, void* d_ws, size_t ws_size,
                              hipStream_t stream){
    const int* ei = (const int*)d_in[1];
    const float* ew = (const float*)d_in[2];

    char* w = (char*)d_ws;
    u16* bufA    = (u16*)w;  w += align256((size_t)N_NODES * 768 * sizeof(u16));
    u16* bufB    = (u16*)w;  w += align256((size_t)N_NODES * 768 * sizeof(u16));
    float* deg   = (float*)w; w += align256(N_NODES * sizeof(float));
    float* dis   = (float*)w; w += align256(N_NODES * sizeof(float));
    int* cnt     = (int*)w;   w += align256(N_NODES * sizeof(int));
    int* off     = (int*)w;   w += align256((N_NODES + 1) * sizeof(int));
    int* cur     = (int*)w;   w += align256(N_NODES * sizeof(int));
    int* esrc    = (int*)w;   w += align256((size_t)N_EDGES * sizeof(int));
    float* enorm = (float*)w; w += align256((size_t)N_EDGES * sizeof(float));
    u16* cvt     = (u16*)w;   w += align256(104076 * sizeof(u16));   // all weights, bf16
    u16* cx      = (u16*)w;   w += align256((size_t)N_NODES * 32 * 12 * sizeof(u16));

    // canonical bf16 weight views (offsets match g_seg_off)
    u16* tc1a_w = cvt + 0;
    u16* tc1a_b = cvt + 12288;
    u16* gc1_w  = cvt + 12416;
    u16* gc1_b  = cvt + 16512;
    u16* tc1b_w = cvt + 16576;
    u16* tc1b_b = cvt + 41152;
    u16* tc2a_w = cvt + 41280;
    u16* tc2a_b = cvt + 65856;
    u16* gc2_w  = cvt + 65984;
    u16* gc2_b  = cvt + 70080;
    u16* tc2b_w = cvt + 70144;
    u16* tc2b_b = cvt + 94720;
    u16* fin_w  = cvt + 94848;
    u16* fin_b  = cvt + 104064;

    // canonicalize fp32 -> bf16
    SmallPtrs ps;
    ps.p[0]  = d_in[3];  ps.p[1]  = d_in[4];   // tc1a_w, tc1a_b
    ps.p[2]  = d_in[5];  ps.p[3]  = d_in[6];   // gc1_w, gc1_b
    ps.p[4]  = d_in[7];  ps.p[5]  = d_in[8];   // tc1b_w, tc1b_b
    ps.p[6]  = d_in[9];  ps.p[7]  = d_in[10];  // tc2a_w, tc2a_b
    ps.p[8]  = d_in[11]; ps.p[9]  = d_in[12];  // gc2_w, gc2_b
    ps.p[10] = d_in[13]; ps.p[11] = d_in[14];  // tc2b_w, tc2b_b
    ps.p[12] = d_in[15]; ps.p[13] = d_in[16];  // fin_w, fin_b
    k_convert_small<<<(104076 + 255) / 256, 256, 0, stream>>>(ps, cvt);
    k_convert_x<<<(N_NODES * 32 * 12 + 255) / 256, 256, 0, stream>>>((const float*)d_in[0], cx);

    // graph prep (shared by both GCN layers)
    k_graph_init<<<(N_NODES + 255) / 256, 256, 0, stream>>>(deg, cnt, cur);
    k_graph_count<<<(N_EDGES + 255) / 256, 256, 0, stream>>>(ei, ew, deg, cnt);
    k_scan<<<1, 1024, 0, stream>>>(cnt, off);
    k_dis<<<(N_NODES + 255) / 256, 256, 0, stream>>>(deg, dis);
    k_scatter<<<(N_EDGES + 255) / 256, 256, 0, stream>>>(ei, ew, dis, off, cur, esrc, enorm);

    // pipeline
    k_gconv<32><<<1250, 256, 0, stream>>>(cx, tc1a_w, tc1a_b, bufA);
    k_agg<<<N_NODES, 192, 0, stream>>>(bufA, bufB, dis, off, esrc, enorm);
    k_mm_bias_relu<<<1250, 256, 0, stream>>>(bufB, gc1_w, gc1_b, bufA);
    k_gconv<64><<<1250, 256, 0, stream>>>(bufA, tc1b_w, tc1b_b, bufB);
    k_gconv<64><<<1250, 256, 0, stream>>>(bufB, tc2a_w, tc2a_b, bufA);
    k_agg<<<N_NODES, 192, 0, stream>>>(bufA, bufB, dis, off, esrc, enorm);
    k_mm_bias_relu<<<1250, 256, 0, stream>>>(bufB, gc2_w, gc2_b, bufA);
    k_gconv<64><<<1250, 256, 0, stream>>>(bufA, tc2b_w, tc2b_b, bufB);
    k_final<<<2500, 256, 0, stream>>>(bufB, fin_w, fin_b, (float*)d_out);
}

// Round 4
// 379.442 us; speedup vs baseline: 1.9716x; 1.9716x over previous
//
#include <hip/hip_runtime.h>
#include <hip/hip_bf16.h>
#include <stdint.h>

#define N_NODES 10000
#define N_EDGES 160000

typedef unsigned short u16;
typedef unsigned int u32;
typedef short s16v8 __attribute__((ext_vector_type(8)));
typedef float f32v4 __attribute__((ext_vector_type(4)));

__device__ __forceinline__ float bf2f(u16 v){ return __uint_as_float(((u32)v) << 16); }
__device__ __forceinline__ float lo16(u32 u){ return __uint_as_float(u << 16); }
__device__ __forceinline__ float hi16(u32 u){ return __uint_as_float(u & 0xffff0000u); }
__device__ __forceinline__ u16 f2bf(float f){
    u32 u = __float_as_uint(f);
    u32 r = (u + 0x7fffu + ((u >> 16) & 1u)) >> 16;
    return (u16)r;
}
__device__ __forceinline__ u32 pack2(float a, float b){
    return (u32)f2bf(a) | ((u32)f2bf(b) << 16);
}

// ---------------- fp32 -> bf16 canonicalization ----------------
__global__ void k_convert_x(const float* __restrict__ src, u16* __restrict__ dst){
    int i = blockIdx.x * blockDim.x + threadIdx.x;
    if (i < N_NODES * 32 * 12) dst[i] = f2bf(src[i]);
}

struct SmallPtrs { const void* p[14]; };

__device__ __constant__ const int g_seg_off[15] = {
    0, 12288, 12416, 16512, 16576, 41152, 41280,
    65856, 65984, 70080, 70144, 94720, 94848, 104064, 104076
};

__global__ void k_convert_small(SmallPtrs ps, u16* __restrict__ dst){
    int i = blockIdx.x * blockDim.x + threadIdx.x;
    if (i >= 104076) return;
    int seg = 0, base = 0;
#pragma unroll
    for (int s = 0; s < 14; s++){
        if (i >= g_seg_off[s]){ seg = s; base = g_seg_off[s]; }
    }
    dst[i] = f2bf(((const float*)ps.p[seg])[i - base]);
}

// ---------------- graph prep ----------------
__global__ void k_graph_init(float* deg, int* cnt, int* cur){
    int i = blockIdx.x * blockDim.x + threadIdx.x;
    if (i < N_NODES){ deg[i] = 1.0f; cnt[i] = 0; cur[i] = 0; }
}

__global__ void k_graph_count(const int* __restrict__ ei, const float* __restrict__ ew,
                              float* deg, int* cnt){
    int e = blockIdx.x * blockDim.x + threadIdx.x;
    if (e < N_EDGES){
        int d = ei[N_EDGES + e];
        atomicAdd(&deg[d], ew[e]);
        atomicAdd(&cnt[d], 1);
    }
}

__global__ void k_scan(const int* __restrict__ cnt, int* __restrict__ off){
    __shared__ int tmp[1024];
    __shared__ int carry;
    int tid = threadIdx.x;
    if (tid == 0) carry = 0;
    __syncthreads();
    for (int base = 0; base < N_NODES; base += 1024){
        int i = base + tid;
        int v = (i < N_NODES) ? cnt[i] : 0;
        tmp[tid] = v;
        __syncthreads();
        for (int s = 1; s < 1024; s <<= 1){
            int t = (tid >= s) ? tmp[tid - s] : 0;
            __syncthreads();
            tmp[tid] += t;
            __syncthreads();
        }
        if (i < N_NODES) off[i] = carry + tmp[tid] - v;   // exclusive
        __syncthreads();
        if (tid == 0) carry += tmp[1023];
        __syncthreads();
    }
    if (tid == 0) off[N_NODES] = carry;
}

__global__ void k_dis(const float* __restrict__ deg, float* __restrict__ dis){
    int i = blockIdx.x * blockDim.x + threadIdx.x;
    if (i < N_NODES) dis[i] = rsqrtf(deg[i]);
}

__global__ void k_scatter(const int* __restrict__ ei, const float* __restrict__ ew,
                          const float* __restrict__ dis, const int* __restrict__ off,
                          int* cur, int* __restrict__ esrc, float* __restrict__ enorm){
    int e = blockIdx.x * blockDim.x + threadIdx.x;
    if (e < N_EDGES){
        int s = ei[e];
        int d = ei[N_EDGES + e];
        float nw = dis[s] * ew[e] * dis[d];
        int p = off[d] + atomicAdd(&cur[d], 1);
        esrc[p] = s;
        enorm[p] = nw;
    }
}

// ---------------- gated temporal conv via MFMA ----------------
// out[(n,t)][o] = sum_d sum_c xT[n][t+d-1][c] * w[o][c][d], then gate P*sigmoid(Q)
// Per block: 8 nodes -> M=96 rows (6 m-tiles), N=128 (wave w owns o in [32w,32w+32)).
// A staged transposed+time-padded in LDS; B (weights) in registers; 16x16x32 bf16 MFMA.
template<int CIN_>
__launch_bounds__(256, 2)
__global__ void k_gconv(const u16* __restrict__ xin, const u16* __restrict__ wg,
                        const u16* __restrict__ bg, u16* __restrict__ out){
    constexpr int KSTEPS = CIN_ / 32;
    constexpr int XPAD = CIN_ + 8;          // row stride: 16B-aligned (144B / 80B)
    __shared__ __attribute__((aligned(16))) u16 xT[8][14][XPAD];
    __shared__ float Qbuf[96 * 65];          // stride 65: bank spread
    u16* Hbuf = (u16*)&xT[0][0][0];          // reused after barrier (12.3KB <= xT size)

    int tid = threadIdx.x;
    int n0 = blockIdx.x * 8;

    // ---- stage xT: x[n][c][t] -> xT[g][1+t][c]; rows 0,13 zero (time pad) ----
    for (int i = tid; i < 8 * XPAD; i += 256){
        int g = i / XPAD, c = i % XPAD;
        xT[g][0][c] = 0; xT[g][13][c] = 0;
    }
    for (int i = tid; i < 8 * CIN_; i += 256){
        int g = i / CIN_, c = i % CIN_;
        const u32* p = (const u32*)(xin + ((size_t)(n0 + g) * CIN_ + c) * 12);
        u32 v0 = p[0], v1 = p[1], v2 = p[2], v3 = p[3], v4 = p[4], v5 = p[5];
        xT[g][1][c]  = (u16)v0;  xT[g][2][c]  = (u16)(v0 >> 16);
        xT[g][3][c]  = (u16)v1;  xT[g][4][c]  = (u16)(v1 >> 16);
        xT[g][5][c]  = (u16)v2;  xT[g][6][c]  = (u16)(v2 >> 16);
        xT[g][7][c]  = (u16)v3;  xT[g][8][c]  = (u16)(v3 >> 16);
        xT[g][9][c]  = (u16)v4;  xT[g][10][c] = (u16)(v4 >> 16);
        xT[g][11][c] = (u16)v5;  xT[g][12][c] = (u16)(v5 >> 16);
    }

    int lane = tid & 63, wave = tid >> 6;
    int col = lane & 15, quad = lane >> 4;

    // ---- B fragments in registers: Bf[d][ks][nt], element j = w[o][c][d], c=ks*32+quad*8+j ----
    s16v8 Bf[3][KSTEPS][2];
#pragma unroll
    for (int nt = 0; nt < 2; nt++){
        int o = wave * 32 + nt * 16 + col;
        const u16* wrow = wg + (size_t)o * (CIN_ * 3);
#pragma unroll
        for (int d = 0; d < 3; d++){
#pragma unroll
            for (int ks = 0; ks < KSTEPS; ks++){
                int c0 = ks * 32 + quad * 8;
                s16v8 b;
#pragma unroll
                for (int j = 0; j < 8; j++) b[j] = (short)wrow[(c0 + j) * 3 + d];
                Bf[d][ks][nt] = b;
            }
        }
    }
    __syncthreads();

    // ---- MFMA main loop ----
    f32v4 acc[6][2];
#pragma unroll
    for (int mt = 0; mt < 6; mt++){ acc[mt][0] = (f32v4)0.f; acc[mt][1] = (f32v4)0.f; }

#pragma unroll
    for (int mt = 0; mt < 6; mt++){
        int m = mt * 16 + col;
        int g = m / 12, t = m - 12 * g;
#pragma unroll
        for (int d = 0; d < 3; d++){
#pragma unroll
            for (int ks = 0; ks < KSTEPS; ks++){
                s16v8 a = *(const s16v8*)&xT[g][t + d][ks * 32 + quad * 8];
                acc[mt][0] = __builtin_amdgcn_mfma_f32_16x16x32_bf16(a, Bf[d][ks][0], acc[mt][0], 0, 0, 0);
                acc[mt][1] = __builtin_amdgcn_mfma_f32_16x16x32_bf16(a, Bf[d][ks][1], acc[mt][1], 0, 0, 0);
            }
        }
    }

    // ---- epilogue: Q waves (2,3) export sigmoid input; P waves (0,1) gate ----
    if (wave >= 2){
#pragma unroll
        for (int nt = 0; nt < 2; nt++){
            int oq = (wave - 2) * 32 + nt * 16 + col;
            float bQ = bf2f(bg[64 + oq]);
#pragma unroll
            for (int mt = 0; mt < 6; mt++){
#pragma unroll
                for (int r = 0; r < 4; r++){
                    int m = mt * 16 + quad * 4 + r;
                    Qbuf[m * 65 + oq] = acc[mt][nt][r] + bQ;
                }
            }
        }
    }
    __syncthreads();
    if (wave < 2){
#pragma unroll
        for (int nt = 0; nt < 2; nt++){
            int o = wave * 32 + nt * 16 + col;
            float bP = bf2f(bg[o]);
#pragma unroll
            for (int mt = 0; mt < 6; mt++){
#pragma unroll
                for (int r = 0; r < 4; r++){
                    int m = mt * 16 + quad * 4 + r;
                    float qv = Qbuf[m * 65 + o];
                    float pv = acc[mt][nt][r] + bP;
                    float hv = pv / (1.f + __expf(-qv));
                    Hbuf[m * 64 + o] = f2bf(hv);     // m = g*12+t
                }
            }
        }
    }
    __syncthreads();

    // ---- coalesced copy-out: Hbuf[g*12+t][o] -> out[n][o][t] ----
    for (int i = tid; i < 8 * 64; i += 256){
        int g = i >> 6, o = i & 63;
        u32* dst = (u32*)(out + ((size_t)(n0 + g) * 64 + o) * 12);
#pragma unroll
        for (int j = 0; j < 6; j++){
            u32 w0 = Hbuf[(g * 12 + 2 * j) * 64 + o];
            u32 w1 = Hbuf[(g * 12 + 2 * j + 1) * 64 + o];
            dst[j] = w0 | (w1 << 16);
        }
    }
}

// ---------------- GCN aggregation: z[n] = dis[n]^2 * x[n] + sum_e norm_e * x[src_e] ----------------
__global__ void k_agg(const u16* __restrict__ x, u16* __restrict__ out,
                      const float* __restrict__ dis, const int* __restrict__ off,
                      const int* __restrict__ esrc, const float* __restrict__ enorm){
    int n = blockIdx.x;
    int v0 = threadIdx.x * 4;       // blockDim = 192, covers 768
    float d = dis[n];
    float sw = d * d;
    const u16* xr = x + (size_t)n * 768 + v0;
    u32 u0 = *(const u32*)xr;
    u32 u1 = *(const u32*)(xr + 2);
    float a0 = sw * lo16(u0), a1 = sw * hi16(u0);
    float a2 = sw * lo16(u1), a3 = sw * hi16(u1);
    int b = off[n], e = off[n + 1];
    for (int p = b; p < e; p++){
        int s = esrc[p];
        float w = enorm[p];
        const u16* q = x + (size_t)s * 768 + v0;
        u32 w0 = *(const u32*)q;
        u32 w1 = *(const u32*)(q + 2);
        a0 = fmaf(w, lo16(w0), a0); a1 = fmaf(w, hi16(w0), a1);
        a2 = fmaf(w, lo16(w1), a2); a3 = fmaf(w, hi16(w1), a3);
    }
    u16* o = out + (size_t)n * 768 + v0;
    *(u32*)o       = pack2(a0, a1);
    *(u32*)(o + 2) = pack2(a2, a3);
}

// ---------------- channel mix + bias + relu ----------------
__launch_bounds__(256, 2)
__global__ void k_mm_bias_relu(const u16* __restrict__ zin, const u16* __restrict__ Wg,
                               const u16* __restrict__ bg, u16* __restrict__ out){
    __shared__ u16 wl[64 * 64];        // [c][o]
    __shared__ float zs[8][64][12];
    int tid = threadIdx.x;
    for (int i = tid; i < 64 * 64; i += 256){
        int o = i >> 6, c = i & 63;
        wl[c * 64 + o] = Wg[i];
    }
    int n0 = blockIdx.x * 8;
    for (int i = tid; i < 8 * 192; i += 256){
        int g = i / 192, r = i % 192;
        int c = r / 3, t4 = (r % 3) * 4;
        const u16* src = zin + ((size_t)(n0 + g) * 64 + c) * 12 + t4;
        u32 u0 = *(const u32*)src;
        u32 u1 = *(const u32*)(src + 2);
        zs[g][c][t4 + 0] = lo16(u0); zs[g][c][t4 + 1] = hi16(u0);
        zs[g][c][t4 + 2] = lo16(u1); zs[g][c][t4 + 3] = hi16(u1);
    }
    __syncthreads();

    int L = tid & 31, g = tid >> 5;
    int n = n0 + g;
    int o0 = 2 * L;
    float a0[12], a1[12];
#pragma unroll
    for (int t = 0; t < 12; t++){ a0[t] = a1[t] = 0.f; }
    for (int c = 0; c < 64; c++){
        u32 uw = *(const u32*)&wl[c * 64 + o0];
        float w0 = lo16(uw), w1 = hi16(uw);
        const float4* zr4 = (const float4*)&zs[g][c][0];
#pragma unroll
        for (int q = 0; q < 3; q++){
            float4 z4 = zr4[q];
            a0[4*q+0] = fmaf(w0, z4.x, a0[4*q+0]); a1[4*q+0] = fmaf(w1, z4.x, a1[4*q+0]);
            a0[4*q+1] = fmaf(w0, z4.y, a0[4*q+1]); a1[4*q+1] = fmaf(w1, z4.y, a1[4*q+1]);
            a0[4*q+2] = fmaf(w0, z4.z, a0[4*q+2]); a1[4*q+2] = fmaf(w1, z4.z, a1[4*q+2]);
            a0[4*q+3] = fmaf(w0, z4.w, a0[4*q+3]); a1[4*q+3] = fmaf(w1, z4.w, a1[4*q+3]);
        }
    }
    float b0 = bf2f(bg[o0]), b1 = bf2f(bg[o0 + 1]);
    u32* o0p = (u32*)(out + ((size_t)n * 64 + o0) * 12);
    u32* o1p = (u32*)(out + ((size_t)n * 64 + o0 + 1) * 12);
#pragma unroll
    for (int i = 0; i < 6; i++){
        float r00 = fmaxf(a0[2*i]   + b0, 0.f);
        float r01 = fmaxf(a0[2*i+1] + b0, 0.f);
        float r10 = fmaxf(a1[2*i]   + b1, 0.f);
        float r11 = fmaxf(a1[2*i+1] + b1, 0.f);
        o0p[i] = pack2(r00, r01);
        o1p[i] = pack2(r10, r11);
    }
}

// ---------------- final conv (fp32 output) ----------------
__launch_bounds__(256)
__global__ void k_final(const u16* __restrict__ h, const u16* __restrict__ fw,
                        const u16* __restrict__ fb, float* __restrict__ out){
    __shared__ u16 wsh[12 * 768];
    int tid = threadIdx.x;
    for (int i = tid; i < 12 * 768; i += 256) wsh[i] = fw[i];
    __syncthreads();
    int lane = tid & 63, wv = tid >> 6;
    int n = blockIdx.x * 4 + wv;
    float hv[12];
    const u16* hr = h + (size_t)n * 768;
#pragma unroll
    for (int j = 0; j < 12; j++) hv[j] = bf2f(hr[lane + 64 * j]);
    float acc[12];
#pragma unroll
    for (int o = 0; o < 12; o++){
        float a = 0.f;
#pragma unroll
        for (int j = 0; j < 12; j++) a = fmaf(hv[j], bf2f(wsh[o * 768 + lane + 64 * j]), a);
        acc[o] = a;
    }
#pragma unroll
    for (int s = 32; s >= 1; s >>= 1){
#pragma unroll
        for (int o = 0; o < 12; o++) acc[o] += __shfl_xor(acc[o], s, 64);
    }
    if (lane == 0){
#pragma unroll
        for (int o = 0; o < 12; o++) out[n * 12 + o] = acc[o] + bf2f(fb[o]);
    }
}

// ---------------- launch ----------------
static inline size_t align256(size_t x){ return (x + 255) & ~(size_t)255; }

extern "C" void kernel_launch(void* const* d_in, const int* in_sizes, int n_in,
                              void* d_out, int out_size, void* d_ws, size_t ws_size,
                              hipStream_t stream){
    const int* ei = (const int*)d_in[1];
    const float* ew = (const float*)d_in[2];

    char* w = (char*)d_ws;
    u16* bufA    = (u16*)w;  w += align256((size_t)N_NODES * 768 * sizeof(u16));
    u16* bufB    = (u16*)w;  w += align256((size_t)N_NODES * 768 * sizeof(u16));
    float* deg   = (float*)w; w += align256(N_NODES * sizeof(float));
    float* dis   = (float*)w; w += align256(N_NODES * sizeof(float));
    int* cnt     = (int*)w;   w += align256(N_NODES * sizeof(int));
    int* off     = (int*)w;   w += align256((N_NODES + 1) * sizeof(int));
    int* cur     = (int*)w;   w += align256(N_NODES * sizeof(int));
    int* esrc    = (int*)w;   w += align256((size_t)N_EDGES * sizeof(int));
    float* enorm = (float*)w; w += align256((size_t)N_EDGES * sizeof(float));
    u16* cvt     = (u16*)w;   w += align256(104076 * sizeof(u16));
    u16* cx      = (u16*)w;   w += align256((size_t)N_NODES * 32 * 12 * sizeof(u16));

    u16* tc1a_w = cvt + 0;
    u16* tc1a_b = cvt + 12288;
    u16* gc1_w  = cvt + 12416;
    u16* gc1_b  = cvt + 16512;
    u16* tc1b_w = cvt + 16576;
    u16* tc1b_b = cvt + 41152;
    u16* tc2a_w = cvt + 41280;
    u16* tc2a_b = cvt + 65856;
    u16* gc2_w  = cvt + 65984;
    u16* gc2_b  = cvt + 70080;
    u16* tc2b_w = cvt + 70144;
    u16* tc2b_b = cvt + 94720;
    u16* fin_w  = cvt + 94848;
    u16* fin_b  = cvt + 104064;

    SmallPtrs ps;
    ps.p[0]  = d_in[3];  ps.p[1]  = d_in[4];
    ps.p[2]  = d_in[5];  ps.p[3]  = d_in[6];
    ps.p[4]  = d_in[7];  ps.p[5]  = d_in[8];
    ps.p[6]  = d_in[9];  ps.p[7]  = d_in[10];
    ps.p[8]  = d_in[11]; ps.p[9]  = d_in[12];
    ps.p[10] = d_in[13]; ps.p[11] = d_in[14];
    ps.p[12] = d_in[15]; ps.p[13] = d_in[16];
    k_convert_small<<<(104076 + 255) / 256, 256, 0, stream>>>(ps, cvt);
    k_convert_x<<<(N_NODES * 32 * 12 + 255) / 256, 256, 0, stream>>>((const float*)d_in[0], cx);

    k_graph_init<<<(N_NODES + 255) / 256, 256, 0, stream>>>(deg, cnt, cur);
    k_graph_count<<<(N_EDGES + 255) / 256, 256, 0, stream>>>(ei, ew, deg, cnt);
    k_scan<<<1, 1024, 0, stream>>>(cnt, off);
    k_dis<<<(N_NODES + 255) / 256, 256, 0, stream>>>(deg, dis);
    k_scatter<<<(N_EDGES + 255) / 256, 256, 0, stream>>>(ei, ew, dis, off, cur, esrc, enorm);

    k_gconv<32><<<1250, 256, 0, stream>>>(cx, tc1a_w, tc1a_b, bufA);
    k_agg<<<N_NODES, 192, 0, stream>>>(bufA, bufB, dis, off, esrc, enorm);
    k_mm_bias_relu<<<1250, 256, 0, stream>>>(bufB, gc1_w, gc1_b, bufA);
    k_gconv<64><<<1250, 256, 0, stream>>>(bufA, tc1b_w, tc1b_b, bufB);
    k_gconv<64><<<1250, 256, 0, stream>>>(bufB, tc2a_w, tc2a_b, bufA);
    k_agg<<<N_NODES, 192, 0, stream>>>(bufA, bufB, dis, off, esrc, enorm);
    k_mm_bias_relu<<<1250, 256, 0, stream>>>(bufB, gc2_w, gc2_b, bufA);
    k_gconv<64><<<1250, 256, 0, stream>>>(bufA, tc2b_w, tc2b_b, bufB);
    k_final<<<2500, 256, 0, stream>>>(bufB, fin_w, fin_b, (float*)d_out);
}

// Round 5
// 274.276 us; speedup vs baseline: 2.7275x; 1.3834x over previous
//
#include <hip/hip_runtime.h>
#include <hip/hip_bf16.h>
#include <stdint.h>

#define N_NODES 10000
#define N_EDGES 160000

typedef unsigned short u16;
typedef unsigned int u32;
typedef short s16v8 __attribute__((ext_vector_type(8)));
typedef float f32v4 __attribute__((ext_vector_type(4)));

__device__ __forceinline__ float bf2f(u16 v){ return __uint_as_float(((u32)v) << 16); }
__device__ __forceinline__ float lo16(u32 u){ return __uint_as_float(u << 16); }
__device__ __forceinline__ float hi16(u32 u){ return __uint_as_float(u & 0xffff0000u); }
__device__ __forceinline__ u16 f2bf(float f){
    u32 u = __float_as_uint(f);
    u32 r = (u + 0x7fffu + ((u >> 16) & 1u)) >> 16;
    return (u16)r;
}
__device__ __forceinline__ u32 pack2(float a, float b){
    return (u32)f2bf(a) | ((u32)f2bf(b) << 16);
}

// ---------------- weights fp32->bf16 + graph-state init (fused) ----------------
struct SmallPtrs { const void* p[14]; };

__device__ __constant__ const int g_seg_off[15] = {
    0, 12288, 12416, 16512, 16576, 41152, 41280,
    65856, 65984, 70080, 70144, 94720, 94848, 104064, 104076
};

__global__ void k_convert_init(SmallPtrs ps, u16* __restrict__ dst,
                               float* deg, int* cnt, int* cur){
    int i = blockIdx.x * blockDim.x + threadIdx.x;
    if (i < 104076){
        int seg = 0, base = 0;
#pragma unroll
        for (int s = 0; s < 14; s++){
            if (i >= g_seg_off[s]){ seg = s; base = g_seg_off[s]; }
        }
        dst[i] = f2bf(((const float*)ps.p[seg])[i - base]);
    }
    if (i < N_NODES){ deg[i] = 1.0f; cnt[i] = 0; cur[i] = 0; }
}

__global__ void k_graph_count(const int* __restrict__ ei, const float* __restrict__ ew,
                              float* deg, int* cnt){
    int e = blockIdx.x * blockDim.x + threadIdx.x;
    if (e < N_EDGES){
        int d = ei[N_EDGES + e];
        atomicAdd(&deg[d], ew[e]);
        atomicAdd(&cnt[d], 1);
    }
}

// single-pass scan (shuffle-based, 2 barriers) + dis, one block of 1024
__global__ void k_scan_dis(const int* __restrict__ cnt, int* __restrict__ off,
                           const float* __restrict__ deg, float* __restrict__ dis){
    __shared__ int wsum[16], woff[16];
    int t = threadIdx.x;
    int lane = t & 63, wv = t >> 6;
    int base = t * 10;                    // threads 0..999 own 10 nodes each
    int loc[10];
    int mysum = 0;
    if (base < N_NODES){
#pragma unroll
        for (int j = 0; j < 10; j++){ loc[j] = mysum; mysum += cnt[base + j]; }
    }
    int s = mysum;                        // inclusive wave scan
#pragma unroll
    for (int d = 1; d < 64; d <<= 1){
        int v = __shfl_up(s, d, 64);
        if (lane >= d) s += v;
    }
    if (lane == 63) wsum[wv] = s;
    __syncthreads();
    if (t < 16){
        int v = wsum[t];
        int sc = v;
#pragma unroll
        for (int d = 1; d < 16; d <<= 1){
            int u = __shfl_up(sc, d, 16);
            if (t >= d) sc += u;
        }
        woff[t] = sc - v;                 // exclusive wave offset
        if (t == 15) off[N_NODES] = sc;
    }
    __syncthreads();
    int tbase = woff[wv] + (s - mysum);
    if (base < N_NODES){
#pragma unroll
        for (int j = 0; j < 10; j++) off[base + j] = tbase + loc[j];
    }
    for (int i = t; i < N_NODES; i += 1024) dis[i] = rsqrtf(deg[i]);
}

__global__ void k_scatter(const int* __restrict__ ei, const float* __restrict__ ew,
                          const float* __restrict__ dis, const int* __restrict__ off,
                          int* cur, int* __restrict__ esrc, float* __restrict__ enorm){
    int e = blockIdx.x * blockDim.x + threadIdx.x;
    if (e < N_EDGES){
        int s = ei[e];
        int d = ei[N_EDGES + e];
        float nw = dis[s] * ew[e] * dis[d];
        int p = off[d] + atomicAdd(&cur[d], 1);
        esrc[p] = s;
        enorm[p] = nw;
    }
}

// ---------------- tc1a: gated conv CIN=32, reads fp32 x, writes [n][t][c] bf16 ----------------
__launch_bounds__(256, 2)
__global__ void k_gconv32(const float* __restrict__ xin, const u16* __restrict__ wg,
                          const u16* __restrict__ bg, u16* __restrict__ out){
    __shared__ __attribute__((aligned(16))) u16 xT[8][14][40];   // time-padded, +8 col pad
    __shared__ __attribute__((aligned(16))) u16 Ho[8][12][72];
    int tid = threadIdx.x;
    int n0 = blockIdx.x * 8;

    for (int i = tid; i < 8 * 40; i += 256){
        int g = i / 40, c = i % 40;
        xT[g][0][c] = 0; xT[g][13][c] = 0;
    }
    {   // one (g,c) per thread: 8*32 = 256
        int g = tid >> 5, c = tid & 31;
        const float4* p = (const float4*)(xin + ((size_t)(n0 + g) * 32 + c) * 12);
        float4 v0 = p[0], v1 = p[1], v2 = p[2];
        xT[g][1][c] = f2bf(v0.x);  xT[g][2][c] = f2bf(v0.y);
        xT[g][3][c] = f2bf(v0.z);  xT[g][4][c] = f2bf(v0.w);
        xT[g][5][c] = f2bf(v1.x);  xT[g][6][c] = f2bf(v1.y);
        xT[g][7][c] = f2bf(v1.z);  xT[g][8][c] = f2bf(v1.w);
        xT[g][9][c] = f2bf(v2.x);  xT[g][10][c] = f2bf(v2.y);
        xT[g][11][c] = f2bf(v2.z); xT[g][12][c] = f2bf(v2.w);
    }
    int lane = tid & 63, wave = tid >> 6;
    int col = lane & 15, quad = lane >> 4;
    int o_p = wave * 16 + col, o_q = o_p + 64;

    s16v8 Bf[3][2];                      // [d][pq]
#pragma unroll
    for (int pq = 0; pq < 2; pq++){
        const u16* wrow = wg + (size_t)(pq ? o_q : o_p) * 96;
#pragma unroll
        for (int d = 0; d < 3; d++){
            s16v8 b;
#pragma unroll
            for (int j = 0; j < 8; j++) b[j] = (short)wrow[(quad * 8 + j) * 3 + d];
            Bf[d][pq] = b;
        }
    }
    __syncthreads();

    f32v4 aP[6], aQ[6];
#pragma unroll
    for (int mt = 0; mt < 6; mt++){ aP[mt] = (f32v4)0.f; aQ[mt] = (f32v4)0.f; }
#pragma unroll
    for (int mt = 0; mt < 6; mt++){
        int m = mt * 16 + col;
        int g = m / 12, t = m - 12 * g;
#pragma unroll
        for (int d = 0; d < 3; d++){
            s16v8 a = *(const s16v8*)&xT[g][t + d][quad * 8];
            aP[mt] = __builtin_amdgcn_mfma_f32_16x16x32_bf16(a, Bf[d][0], aP[mt], 0, 0, 0);
            aQ[mt] = __builtin_amdgcn_mfma_f32_16x16x32_bf16(a, Bf[d][1], aQ[mt], 0, 0, 0);
        }
    }
    float bP = bf2f(bg[o_p]), bQ = bf2f(bg[o_q]);
#pragma unroll
    for (int mt = 0; mt < 6; mt++){
#pragma unroll
        for (int r = 0; r < 4; r++){
            int m2 = mt * 16 + quad * 4 + r;
            int g = m2 / 12, t = m2 - 12 * g;
            float pv = aP[mt][r] + bP, qv = aQ[mt][r] + bQ;
            Ho[g][t][o_p] = f2bf(pv / (1.f + __expf(-qv)));
        }
    }
    __syncthreads();
    for (int i = tid; i < 768; i += 256){            // 16B chunks: [n][t][c]
        int g = i / 96, r = i % 96, t = r / 8, ch = r % 8;
        *(s16v8*)(out + (size_t)(n0 + g) * 768 + t * 64 + ch * 8) = *(const s16v8*)&Ho[g][t][ch * 8];
    }
}

// ---------------- GCN aggregation (layout-agnostic over 768-vec) ----------------
__global__ void k_agg(const u16* __restrict__ x, u16* __restrict__ out,
                      const float* __restrict__ dis, const int* __restrict__ off,
                      const int* __restrict__ esrc, const float* __restrict__ enorm){
    int n = blockIdx.x;
    int v0 = threadIdx.x * 4;       // blockDim = 192
    float d = dis[n];
    float sw = d * d;
    const u16* xr = x + (size_t)n * 768 + v0;
    u32 u0 = *(const u32*)xr;
    u32 u1 = *(const u32*)(xr + 2);
    float a0 = sw * lo16(u0), a1 = sw * hi16(u0);
    float a2 = sw * lo16(u1), a3 = sw * hi16(u1);
    int b = off[n], e = off[n + 1];
    for (int p = b; p < e; p++){
        int s = esrc[p];
        float w = enorm[p];
        const u16* q = x + (size_t)s * 768 + v0;
        u32 w0 = *(const u32*)q;
        u32 w1 = *(const u32*)(q + 2);
        a0 = fmaf(w, lo16(w0), a0); a1 = fmaf(w, hi16(w0), a1);
        a2 = fmaf(w, lo16(w1), a2); a3 = fmaf(w, hi16(w1), a3);
    }
    u16* o = out + (size_t)n * 768 + v0;
    *(u32*)o       = pack2(a0, a1);
    *(u32*)(o + 2) = pack2(a2, a3);
}

// ---------------- fused per-node chain ----------------
// MID : mix(relu) -> gated conv w1 -> gated conv w2 -> out [n][t][c]
// LAST: mix(relu) -> gated conv w1 -> final 12x768 dot -> fp32 out
#define XIDX(g, row, c) (((g) * 14 + (row)) * 72 + (c))

template<bool LAST>
__launch_bounds__(256, 2)
__global__ void k_fused(const u16* __restrict__ z,      // [n][t][c] bf16
                        const u16* __restrict__ Wmix, const u16* __restrict__ bmix,
                        const u16* __restrict__ w1, const u16* __restrict__ b1,
                        const u16* __restrict__ w2, const u16* __restrict__ b2,
                        const u16* __restrict__ fw, const u16* __restrict__ fb,
                        u16* __restrict__ outMid, float* __restrict__ outFin){
    __shared__ __attribute__((aligned(16))) u16 bufX[8 * 14 * 72];
    __shared__ __attribute__((aligned(16))) u16 bufY[8 * 14 * 72];
    int tid = threadIdx.x;
    int n0 = blockIdx.x * 8;
    int lane = tid & 63, wave = tid >> 6;
    int col = lane & 15, quad = lane >> 4;

    // zero time-pad rows of both buffers
    for (int i = tid; i < 8 * 72; i += 256){
        int g = i / 72, c = i % 72;
        bufX[XIDX(g, 0, c)] = 0; bufX[XIDX(g, 13, c)] = 0;
        bufY[XIDX(g, 0, c)] = 0; bufY[XIDX(g, 13, c)] = 0;
    }
    // stage z -> bufX rows 1..12 (straight 16B copies; layout matches)
    for (int i = tid; i < 768; i += 256){
        int g = i / 96, r = i % 96, t = r / 8, ch = r % 8;
        *(s16v8*)&bufX[XIDX(g, 1 + t, ch * 8)] =
            *(const s16v8*)(z + (size_t)(n0 + g) * 768 + t * 64 + ch * 8);
    }
    // ---- mix B frags (N=64: one 16-col tile per wave) ----
    int o_mix = wave * 16 + col;
    s16v8 Bm[2];
#pragma unroll
    for (int ks = 0; ks < 2; ks++)
        Bm[ks] = *(const s16v8*)(Wmix + (size_t)o_mix * 64 + ks * 32 + quad * 8);
    __syncthreads();

    // ---- mix MFMA: y = relu(z*W + b), bufX -> bufY ----
    {
        f32v4 accm[6];
#pragma unroll
        for (int mt = 0; mt < 6; mt++) accm[mt] = (f32v4)0.f;
#pragma unroll
        for (int mt = 0; mt < 6; mt++){
            int m = mt * 16 + col;
            int g = m / 12, t = m - 12 * g;
#pragma unroll
            for (int ks = 0; ks < 2; ks++){
                s16v8 a = *(const s16v8*)&bufX[XIDX(g, 1 + t, ks * 32 + quad * 8)];
                accm[mt] = __builtin_amdgcn_mfma_f32_16x16x32_bf16(a, Bm[ks], accm[mt], 0, 0, 0);
            }
        }
        float bm = bf2f(bmix[o_mix]);
#pragma unroll
        for (int mt = 0; mt < 6; mt++){
#pragma unroll
            for (int r = 0; r < 4; r++){
                int m2 = mt * 16 + quad * 4 + r;
                int g = m2 / 12, t = m2 - 12 * g;
                bufY[XIDX(g, 1 + t, o_mix)] = f2bf(fmaxf(accm[mt][r] + bm, 0.f));
            }
        }
    }
    __syncthreads();

    // ---- gated conv 1: bufY -> (MID: bufX rows) / (LAST: H2 layout in bufX) ----
    {
        int o_p = wave * 16 + col, o_q = o_p + 64;
        s16v8 Bf[3][2][2];                 // [d][ks][pq]
#pragma unroll
        for (int pq = 0; pq < 2; pq++){
            const u16* wrow = w1 + (size_t)(pq ? o_q : o_p) * 192;
#pragma unroll
            for (int d = 0; d < 3; d++)
#pragma unroll
                for (int ks = 0; ks < 2; ks++){
                    s16v8 b;
#pragma unroll
                    for (int j = 0; j < 8; j++) b[j] = (short)wrow[(ks * 32 + quad * 8 + j) * 3 + d];
                    Bf[d][ks][pq] = b;
                }
        }
        f32v4 aP[6], aQ[6];
#pragma unroll
        for (int mt = 0; mt < 6; mt++){ aP[mt] = (f32v4)0.f; aQ[mt] = (f32v4)0.f; }
#pragma unroll
        for (int mt = 0; mt < 6; mt++){
            int m = mt * 16 + col;
            int g = m / 12, t = m - 12 * g;
#pragma unroll
            for (int d = 0; d < 3; d++)
#pragma unroll
                for (int ks = 0; ks < 2; ks++){
                    s16v8 a = *(const s16v8*)&bufY[XIDX(g, t + d, ks * 32 + quad * 8)];
                    aP[mt] = __builtin_amdgcn_mfma_f32_16x16x32_bf16(a, Bf[d][ks][0], aP[mt], 0, 0, 0);
                    aQ[mt] = __builtin_amdgcn_mfma_f32_16x16x32_bf16(a, Bf[d][ks][1], aQ[mt], 0, 0, 0);
                }
        }
        float bP = bf2f(b1[o_p]), bQ = bf2f(b1[o_q]);
#pragma unroll
        for (int mt = 0; mt < 6; mt++){
#pragma unroll
            for (int r = 0; r < 4; r++){
                int m2 = mt * 16 + quad * 4 + r;
                int g = m2 / 12, t = m2 - 12 * g;
                float pv = aP[mt][r] + bP, qv = aQ[mt][r] + bQ;
                u16 hv = f2bf(pv / (1.f + __expf(-qv)));
                if (LAST) bufX[g * 1008 + o_p * 12 + t] = hv;   // H2[g][c*12+t]
                else      bufX[XIDX(g, 1 + t, o_p)] = hv;
            }
        }
    }
    __syncthreads();

    if (!LAST){
        // ---- gated conv 2: bufX -> bufY ----
        int o_p = wave * 16 + col, o_q = o_p + 64;
        s16v8 Bf[3][2][2];
#pragma unroll
        for (int pq = 0; pq < 2; pq++){
            const u16* wrow = w2 + (size_t)(pq ? o_q : o_p) * 192;
#pragma unroll
            for (int d = 0; d < 3; d++)
#pragma unroll
                for (int ks = 0; ks < 2; ks++){
                    s16v8 b;
#pragma unroll
                    for (int j = 0; j < 8; j++) b[j] = (short)wrow[(ks * 32 + quad * 8 + j) * 3 + d];
                    Bf[d][ks][pq] = b;
                }
        }
        f32v4 aP[6], aQ[6];
#pragma unroll
        for (int mt = 0; mt < 6; mt++){ aP[mt] = (f32v4)0.f; aQ[mt] = (f32v4)0.f; }
#pragma unroll
        for (int mt = 0; mt < 6; mt++){
            int m = mt * 16 + col;
            int g = m / 12, t = m - 12 * g;
#pragma unroll
            for (int d = 0; d < 3; d++)
#pragma unroll
                for (int ks = 0; ks < 2; ks++){
                    s16v8 a = *(const s16v8*)&bufX[XIDX(g, t + d, ks * 32 + quad * 8)];
                    aP[mt] = __builtin_amdgcn_mfma_f32_16x16x32_bf16(a, Bf[d][ks][0], aP[mt], 0, 0, 0);
                    aQ[mt] = __builtin_amdgcn_mfma_f32_16x16x32_bf16(a, Bf[d][ks][1], aQ[mt], 0, 0, 0);
                }
        }
        float bP = bf2f(b2[o_p]), bQ = bf2f(b2[o_q]);
#pragma unroll
        for (int mt = 0; mt < 6; mt++){
#pragma unroll
            for (int r = 0; r < 4; r++){
                int m2 = mt * 16 + quad * 4 + r;
                int g = m2 / 12, t = m2 - 12 * g;
                float pv = aP[mt][r] + bP, qv = aQ[mt][r] + bQ;
                bufY[XIDX(g, 1 + t, o_p)] = f2bf(pv / (1.f + __expf(-qv)));
            }
        }
        __syncthreads();
        for (int i = tid; i < 768; i += 256){
            int g = i / 96, r = i % 96, t = r / 8, ch = r % 8;
            *(s16v8*)(outMid + (size_t)(n0 + g) * 768 + t * 64 + ch * 8) =
                *(const s16v8*)&bufY[XIDX(g, 1 + t, ch * 8)];
        }
    } else {
        // ---- final: out[g][o] = sum_{k=c*12+t} H2[g][k]*fw[o][k] + fb[o] (wave 0 only) ----
        if (wave == 0){
            f32v4 accF = {0.f, 0.f, 0.f, 0.f};
            int g8 = col & 7;
#pragma unroll
            for (int ks = 0; ks < 24; ks++){
                s16v8 a = *(const s16v8*)&bufX[g8 * 1008 + ks * 32 + quad * 8];
                s16v8 bfr = {0, 0, 0, 0, 0, 0, 0, 0};
                if (col < 12)
                    bfr = *(const s16v8*)(fw + (size_t)col * 768 + ks * 32 + quad * 8);
                accF = __builtin_amdgcn_mfma_f32_16x16x32_bf16(a, bfr, accF, 0, 0, 0);
            }
            if (col < 12){
                float bb = bf2f(fb[col]);
#pragma unroll
                for (int r = 0; r < 4; r++){
                    int g = quad * 4 + r;
                    if (g < 8) outFin[(size_t)(n0 + g) * 12 + col] = accF[r] + bb;
                }
            }
        }
    }
}

// ---------------- launch ----------------
static inline size_t align256(size_t x){ return (x + 255) & ~(size_t)255; }

extern "C" void kernel_launch(void* const* d_in, const int* in_sizes, int n_in,
                              void* d_out, int out_size, void* d_ws, size_t ws_size,
                              hipStream_t stream){
    const float* x  = (const float*)d_in[0];
    const int* ei   = (const int*)d_in[1];
    const float* ew = (const float*)d_in[2];

    char* w = (char*)d_ws;
    u16* bufA    = (u16*)w;  w += align256((size_t)N_NODES * 768 * sizeof(u16));
    u16* bufB    = (u16*)w;  w += align256((size_t)N_NODES * 768 * sizeof(u16));
    float* deg   = (float*)w; w += align256(N_NODES * sizeof(float));
    float* dis   = (float*)w; w += align256(N_NODES * sizeof(float));
    int* cnt     = (int*)w;   w += align256(N_NODES * sizeof(int));
    int* off     = (int*)w;   w += align256((N_NODES + 1) * sizeof(int));
    int* cur     = (int*)w;   w += align256(N_NODES * sizeof(int));
    int* esrc    = (int*)w;   w += align256((size_t)N_EDGES * sizeof(int));
    float* enorm = (float*)w; w += align256((size_t)N_EDGES * sizeof(float));
    u16* cvt     = (u16*)w;   w += align256(104076 * sizeof(u16));

    u16* tc1a_w = cvt + 0;
    u16* tc1a_b = cvt + 12288;
    u16* gc1_w  = cvt + 12416;
    u16* gc1_b  = cvt + 16512;
    u16* tc1b_w = cvt + 16576;
    u16* tc1b_b = cvt + 41152;
    u16* tc2a_w = cvt + 41280;
    u16* tc2a_b = cvt + 65856;
    u16* gc2_w  = cvt + 65984;
    u16* gc2_b  = cvt + 70080;
    u16* tc2b_w = cvt + 70144;
    u16* tc2b_b = cvt + 94720;
    u16* fin_w  = cvt + 94848;
    u16* fin_b  = cvt + 104064;

    SmallPtrs ps;
    ps.p[0]  = d_in[3];  ps.p[1]  = d_in[4];
    ps.p[2]  = d_in[5];  ps.p[3]  = d_in[6];
    ps.p[4]  = d_in[7];  ps.p[5]  = d_in[8];
    ps.p[6]  = d_in[9];  ps.p[7]  = d_in[10];
    ps.p[8]  = d_in[11]; ps.p[9]  = d_in[12];
    ps.p[10] = d_in[13]; ps.p[11] = d_in[14];
    ps.p[12] = d_in[15]; ps.p[13] = d_in[16];

    k_convert_init<<<(104076 + 255) / 256, 256, 0, stream>>>(ps, cvt, deg, cnt, cur);
    k_graph_count<<<(N_EDGES + 255) / 256, 256, 0, stream>>>(ei, ew, deg, cnt);
    k_scan_dis<<<1, 1024, 0, stream>>>(cnt, off, deg, dis);
    k_scatter<<<(N_EDGES + 255) / 256, 256, 0, stream>>>(ei, ew, dis, off, cur, esrc, enorm);

    k_gconv32<<<1250, 256, 0, stream>>>(x, tc1a_w, tc1a_b, bufA);
    k_agg<<<N_NODES, 192, 0, stream>>>(bufA, bufB, dis, off, esrc, enorm);
    k_fused<false><<<1250, 256, 0, stream>>>(bufB, gc1_w, gc1_b, tc1b_w, tc1b_b,
                                             tc2a_w, tc2a_b, nullptr, nullptr,
                                             bufA, nullptr);
    k_agg<<<N_NODES, 192, 0, stream>>>(bufA, bufB, dis, off, esrc, enorm);
    k_fused<true><<<1250, 256, 0, stream>>>(bufB, gc2_w, gc2_b, tc2b_w, tc2b_b,
                                            nullptr, nullptr, fin_w, fin_b,
                                            nullptr, (float*)d_out);
}

// Round 6
// 266.626 us; speedup vs baseline: 2.8058x; 1.0287x over previous
//
#include <hip/hip_runtime.h>
#include <hip/hip_bf16.h>
#include <stdint.h>

#define N_NODES 10000
#define N_EDGES 160000

typedef unsigned short u16;
typedef unsigned int u32;
typedef short s16v8 __attribute__((ext_vector_type(8)));
typedef float f32v4 __attribute__((ext_vector_type(4)));

__device__ __forceinline__ float bf2f(u16 v){ return __uint_as_float(((u32)v) << 16); }
__device__ __forceinline__ u16 f2bf(float f){
    u32 u = __float_as_uint(f);
    u32 r = (u + 0x7fffu + ((u >> 16) & 1u)) >> 16;
    return (u16)r;
}

// ---------------- weights fp32->bf16 (+tconv transpose to [d][o][c]) + graph init ----------------
struct SmallPtrs { const void* p[14]; };

__device__ __constant__ const int g_seg_off[15] = {
    0, 12288, 12416, 16512, 16576, 41152, 41280,
    65856, 65984, 70080, 70144, 94720, 94848, 104064, 104076
};
// 0=straight, 1=tconv CIN=32 transpose, 2=tconv CIN=64 transpose
__device__ __constant__ const int g_seg_kind[14] = {
    1, 0, 0, 0, 2, 0, 2, 0, 0, 0, 2, 0, 0, 0
};

__global__ void k_convert_init(SmallPtrs ps, u16* __restrict__ dst,
                               float* deg, int* cnt, int* cur){
    int i = blockIdx.x * blockDim.x + threadIdx.x;
    if (i < 104076){
        int seg = 0, base = 0;
#pragma unroll
        for (int s = 0; s < 14; s++){
            if (i >= g_seg_off[s]){ seg = s; base = g_seg_off[s]; }
        }
        int li = i - base;
        float v = ((const float*)ps.p[seg])[li];
        int kind = g_seg_kind[seg];
        int dsto = li;
        if (kind){
            int CIN = (kind == 1) ? 32 : 64;
            int o = li / (3 * CIN);
            int rem = li - o * (3 * CIN);
            int c = rem / 3, d = rem - c * 3;
            dsto = d * 128 * CIN + o * CIN + c;     // [d][o][c]
        }
        dst[base + dsto] = f2bf(v);
    }
    if (i < N_NODES){ deg[i] = 1.0f; cnt[i] = 0; cur[i] = 0; }
}

// ---------------- merged: gconv32 (blocks 0..1249) || edge count (blocks 1250..1874) ----------------
// gconv32: reads fp32 x [n][32][12], w [d][128][32] bf16, writes [n][t*64+c] bf16
__launch_bounds__(256, 2)
__global__ void k_gconv_count(const float* __restrict__ xin, const u16* __restrict__ wg,
                              const u16* __restrict__ bg, u16* __restrict__ out,
                              const int* __restrict__ ei, const float* __restrict__ ew,
                              float* deg, int* cnt){
    if (blockIdx.x >= 1250){
        int e = (blockIdx.x - 1250) * 256 + threadIdx.x;
        if (e < N_EDGES){
            int d = ei[N_EDGES + e];
            atomicAdd(&deg[d], ew[e]);
            atomicAdd(&cnt[d], 1);
        }
        return;
    }
    __shared__ __attribute__((aligned(16))) u16 xT[8][14][40];
    __shared__ __attribute__((aligned(16))) u16 Ho[8][12][72];
    int tid = threadIdx.x;
    int n0 = blockIdx.x * 8;

    for (int i = tid; i < 8 * 40; i += 256){
        int g = i / 40, c = i % 40;
        xT[g][0][c] = 0; xT[g][13][c] = 0;
    }
    {
        int g = tid >> 5, c = tid & 31;
        const float4* p = (const float4*)(xin + ((size_t)(n0 + g) * 32 + c) * 12);
        float4 v0 = p[0], v1 = p[1], v2 = p[2];
        xT[g][1][c] = f2bf(v0.x);  xT[g][2][c] = f2bf(v0.y);
        xT[g][3][c] = f2bf(v0.z);  xT[g][4][c] = f2bf(v0.w);
        xT[g][5][c] = f2bf(v1.x);  xT[g][6][c] = f2bf(v1.y);
        xT[g][7][c] = f2bf(v1.z);  xT[g][8][c] = f2bf(v1.w);
        xT[g][9][c] = f2bf(v2.x);  xT[g][10][c] = f2bf(v2.y);
        xT[g][11][c] = f2bf(v2.z); xT[g][12][c] = f2bf(v2.w);
    }
    int lane = tid & 63, wave = tid >> 6;
    int col = lane & 15, quad = lane >> 4;
    int o_p = wave * 16 + col, o_q = o_p + 64;

    s16v8 Bf[3][2];
#pragma unroll
    for (int pq = 0; pq < 2; pq++){
        int o = pq ? o_q : o_p;
#pragma unroll
        for (int d = 0; d < 3; d++)
            Bf[d][pq] = *(const s16v8*)(wg + d * 4096 + o * 32 + quad * 8);
    }
    __syncthreads();

    f32v4 aP[6], aQ[6];
#pragma unroll
    for (int mt = 0; mt < 6; mt++){ aP[mt] = (f32v4)0.f; aQ[mt] = (f32v4)0.f; }
#pragma unroll
    for (int mt = 0; mt < 6; mt++){
        int m = mt * 16 + col;
        int g = m / 12, t = m - 12 * g;
#pragma unroll
        for (int d = 0; d < 3; d++){
            s16v8 a = *(const s16v8*)&xT[g][t + d][quad * 8];
            aP[mt] = __builtin_amdgcn_mfma_f32_16x16x32_bf16(a, Bf[d][0], aP[mt], 0, 0, 0);
            aQ[mt] = __builtin_amdgcn_mfma_f32_16x16x32_bf16(a, Bf[d][1], aQ[mt], 0, 0, 0);
        }
    }
    float bP = bf2f(bg[o_p]), bQ = bf2f(bg[o_q]);
#pragma unroll
    for (int mt = 0; mt < 6; mt++){
#pragma unroll
        for (int r = 0; r < 4; r++){
            int m2 = mt * 16 + quad * 4 + r;
            int g = m2 / 12, t = m2 - 12 * g;
            float pv = aP[mt][r] + bP, qv = aQ[mt][r] + bQ;
            Ho[g][t][o_p] = f2bf(pv / (1.f + __expf(-qv)));
        }
    }
    __syncthreads();
    for (int i = tid; i < 768; i += 256){
        int g = i / 96, r = i % 96, t = r / 8, ch = r % 8;
        *(s16v8*)(out + (size_t)(n0 + g) * 768 + t * 64 + ch * 8) = *(const s16v8*)&Ho[g][t][ch * 8];
    }
}

// single-pass scan (shuffle-based) + dis, one block of 1024
__global__ void k_scan_dis(const int* __restrict__ cnt, int* __restrict__ off,
                           const float* __restrict__ deg, float* __restrict__ dis){
    __shared__ int wsum[16], woff[16];
    int t = threadIdx.x;
    int lane = t & 63, wv = t >> 6;
    int base = t * 10;
    int loc[10];
    int mysum = 0;
    if (base < N_NODES){
#pragma unroll
        for (int j = 0; j < 10; j++){ loc[j] = mysum; mysum += cnt[base + j]; }
    }
    int s = mysum;
#pragma unroll
    for (int d = 1; d < 64; d <<= 1){
        int v = __shfl_up(s, d, 64);
        if (lane >= d) s += v;
    }
    if (lane == 63) wsum[wv] = s;
    __syncthreads();
    if (t < 16){
        int v = wsum[t];
        int sc = v;
#pragma unroll
        for (int d = 1; d < 16; d <<= 1){
            int u = __shfl_up(sc, d, 16);
            if (t >= d) sc += u;
        }
        woff[t] = sc - v;
        if (t == 15) off[N_NODES] = sc;
    }
    __syncthreads();
    int tbase = woff[wv] + (s - mysum);
    if (base < N_NODES){
#pragma unroll
        for (int j = 0; j < 10; j++) off[base + j] = tbase + loc[j];
    }
    for (int i = t; i < N_NODES; i += 1024) dis[i] = rsqrtf(deg[i]);
}

__global__ void k_scatter(const int* __restrict__ ei, const float* __restrict__ ew,
                          const float* __restrict__ dis, const int* __restrict__ off,
                          int* cur, int2* __restrict__ epack){
    int e = blockIdx.x * blockDim.x + threadIdx.x;
    if (e < N_EDGES){
        int s = ei[e];
        int d = ei[N_EDGES + e];
        float nw = dis[s] * ew[e] * dis[d];
        int p = off[d] + atomicAdd(&cur[d], 1);
        epack[p] = make_int2(s, __float_as_int(nw));
    }
}

// ---------------- fused: [gather-agg] -> mix(relu) -> gconv w1 -> (MID: gconv w2 | LAST: final) ----------------
#define XIDX(g, row, c) (((g) * 14 + (row)) * 72 + (c))

template<bool LAST>
__launch_bounds__(256, 2)
__global__ void k_fused(const u16* __restrict__ src,    // [n][t*64+c] bf16 feature source for gather
                        const float* __restrict__ dis, const int* __restrict__ off,
                        const int2* __restrict__ ep,
                        const u16* __restrict__ Wmix, const u16* __restrict__ bmix,
                        const u16* __restrict__ w1, const u16* __restrict__ b1,
                        const u16* __restrict__ w2, const u16* __restrict__ b2,
                        const u16* __restrict__ fw, const u16* __restrict__ fb,
                        u16* __restrict__ outMid, float* __restrict__ outFin){
    __shared__ __attribute__((aligned(16))) u16 bufX[8 * 14 * 72];
    __shared__ __attribute__((aligned(16))) u16 bufY[8 * 14 * 72];
    int tid = threadIdx.x;
    int n0 = blockIdx.x * 8;
    int lane = tid & 63, wave = tid >> 6;
    int col = lane & 15, quad = lane >> 4;

    // zero time-pad rows
    for (int i = tid; i < 8 * 72; i += 256){
        int g = i / 72, c = i % 72;
        bufX[XIDX(g, 0, c)] = 0; bufX[XIDX(g, 13, c)] = 0;
        bufY[XIDX(g, 0, c)] = 0; bufY[XIDX(g, 13, c)] = 0;
    }

    // ---- fused GCN aggregation: 32 threads/node, 24 fp32 acc each ----
    {
        int g = tid >> 5, j = tid & 31;
        int n = n0 + g;
        float dv = dis[n];
        float sw = dv * dv;
        const u16* xr = src + (size_t)n * 768 + j * 24;
        float acc[24];
#pragma unroll
        for (int k = 0; k < 3; k++){
            s16v8 v = *(const s16v8*)(xr + k * 8);
#pragma unroll
            for (int q = 0; q < 8; q++) acc[k * 8 + q] = sw * bf2f((u16)v[q]);
        }
        int b = off[n], e = off[n + 1];
        for (int p = b; p < e; p++){
            int2 pr = ep[p];
            float w = __int_as_float(pr.y);
            const u16* qr = src + (size_t)pr.x * 768 + j * 24;
#pragma unroll
            for (int k = 0; k < 3; k++){
                s16v8 v = *(const s16v8*)(qr + k * 8);
#pragma unroll
                for (int q = 0; q < 8; q++) acc[k * 8 + q] = fmaf(w, bf2f((u16)v[q]), acc[k * 8 + q]);
            }
        }
#pragma unroll
        for (int k = 0; k < 3; k++){
            int flat = j * 24 + k * 8;
            int t = flat >> 6, c = flat & 63;
            s16v8 hv;
#pragma unroll
            for (int q = 0; q < 8; q++) hv[q] = (short)f2bf(acc[k * 8 + q]);
            *(s16v8*)&bufX[XIDX(g, 1 + t, c)] = hv;
        }
    }

    // ---- mix B frags ----
    int o_mix = wave * 16 + col;
    s16v8 Bm[2];
#pragma unroll
    for (int ks = 0; ks < 2; ks++)
        Bm[ks] = *(const s16v8*)(Wmix + (size_t)o_mix * 64 + ks * 32 + quad * 8);
    __syncthreads();

    // ---- mix MFMA: y = relu(z*W + b) ----
    {
        f32v4 accm[6];
#pragma unroll
        for (int mt = 0; mt < 6; mt++) accm[mt] = (f32v4)0.f;
#pragma unroll
        for (int mt = 0; mt < 6; mt++){
            int m = mt * 16 + col;
            int g = m / 12, t = m - 12 * g;
#pragma unroll
            for (int ks = 0; ks < 2; ks++){
                s16v8 a = *(const s16v8*)&bufX[XIDX(g, 1 + t, ks * 32 + quad * 8)];
                accm[mt] = __builtin_amdgcn_mfma_f32_16x16x32_bf16(a, Bm[ks], accm[mt], 0, 0, 0);
            }
        }
        float bm = bf2f(bmix[o_mix]);
#pragma unroll
        for (int mt = 0; mt < 6; mt++){
#pragma unroll
            for (int r = 0; r < 4; r++){
                int m2 = mt * 16 + quad * 4 + r;
                int g = m2 / 12, t = m2 - 12 * g;
                bufY[XIDX(g, 1 + t, o_mix)] = f2bf(fmaxf(accm[mt][r] + bm, 0.f));
            }
        }
    }
    __syncthreads();

    // ---- gated conv 1: bufY -> bufX ----
    {
        int o_p = wave * 16 + col, o_q = o_p + 64;
        s16v8 Bf[3][2][2];
#pragma unroll
        for (int pq = 0; pq < 2; pq++){
            int o = pq ? o_q : o_p;
#pragma unroll
            for (int d = 0; d < 3; d++)
#pragma unroll
                for (int ks = 0; ks < 2; ks++)
                    Bf[d][ks][pq] = *(const s16v8*)(w1 + d * 8192 + o * 64 + ks * 32 + quad * 8);
        }
        f32v4 aP[6], aQ[6];
#pragma unroll
        for (int mt = 0; mt < 6; mt++){ aP[mt] = (f32v4)0.f; aQ[mt] = (f32v4)0.f; }
#pragma unroll
        for (int mt = 0; mt < 6; mt++){
            int m = mt * 16 + col;
            int g = m / 12, t = m - 12 * g;
#pragma unroll
            for (int d = 0; d < 3; d++)
#pragma unroll
                for (int ks = 0; ks < 2; ks++){
                    s16v8 a = *(const s16v8*)&bufY[XIDX(g, t + d, ks * 32 + quad * 8)];
                    aP[mt] = __builtin_amdgcn_mfma_f32_16x16x32_bf16(a, Bf[d][ks][0], aP[mt], 0, 0, 0);
                    aQ[mt] = __builtin_amdgcn_mfma_f32_16x16x32_bf16(a, Bf[d][ks][1], aQ[mt], 0, 0, 0);
                }
        }
        float bP = bf2f(b1[o_p]), bQ = bf2f(b1[o_q]);
#pragma unroll
        for (int mt = 0; mt < 6; mt++){
#pragma unroll
            for (int r = 0; r < 4; r++){
                int m2 = mt * 16 + quad * 4 + r;
                int g = m2 / 12, t = m2 - 12 * g;
                float pv = aP[mt][r] + bP, qv = aQ[mt][r] + bQ;
                u16 hv = f2bf(pv / (1.f + __expf(-qv)));
                if (LAST) bufX[g * 1008 + o_p * 12 + t] = hv;   // H2[g][c*12+t]
                else      bufX[XIDX(g, 1 + t, o_p)] = hv;
            }
        }
    }
    __syncthreads();

    if (!LAST){
        // ---- gated conv 2: bufX -> bufY -> outMid ----
        int o_p = wave * 16 + col, o_q = o_p + 64;
        s16v8 Bf[3][2][2];
#pragma unroll
        for (int pq = 0; pq < 2; pq++){
            int o = pq ? o_q : o_p;
#pragma unroll
            for (int d = 0; d < 3; d++)
#pragma unroll
                for (int ks = 0; ks < 2; ks++)
                    Bf[d][ks][pq] = *(const s16v8*)(w2 + d * 8192 + o * 64 + ks * 32 + quad * 8);
        }
        f32v4 aP[6], aQ[6];
#pragma unroll
        for (int mt = 0; mt < 6; mt++){ aP[mt] = (f32v4)0.f; aQ[mt] = (f32v4)0.f; }
#pragma unroll
        for (int mt = 0; mt < 6; mt++){
            int m = mt * 16 + col;
            int g = m / 12, t = m - 12 * g;
#pragma unroll
            for (int d = 0; d < 3; d++)
#pragma unroll
                for (int ks = 0; ks < 2; ks++){
                    s16v8 a = *(const s16v8*)&bufX[XIDX(g, t + d, ks * 32 + quad * 8)];
                    aP[mt] = __builtin_amdgcn_mfma_f32_16x16x32_bf16(a, Bf[d][ks][0], aP[mt], 0, 0, 0);
                    aQ[mt] = __builtin_amdgcn_mfma_f32_16x16x32_bf16(a, Bf[d][ks][1], aQ[mt], 0, 0, 0);
                }
        }
        float bP = bf2f(b2[o_p]), bQ = bf2f(b2[o_q]);
#pragma unroll
        for (int mt = 0; mt < 6; mt++){
#pragma unroll
            for (int r = 0; r < 4; r++){
                int m2 = mt * 16 + quad * 4 + r;
                int g = m2 / 12, t = m2 - 12 * g;
                float pv = aP[mt][r] + bP, qv = aQ[mt][r] + bQ;
                bufY[XIDX(g, 1 + t, o_p)] = f2bf(pv / (1.f + __expf(-qv)));
            }
        }
        __syncthreads();
        for (int i = tid; i < 768; i += 256){
            int g = i / 96, r = i % 96, t = r / 8, ch = r % 8;
            *(s16v8*)(outMid + (size_t)(n0 + g) * 768 + t * 64 + ch * 8) =
                *(const s16v8*)&bufY[XIDX(g, 1 + t, ch * 8)];
        }
    } else {
        // ---- final: out[g][o] = sum_k H2[g][k]*fw[o][k] + fb[o] (wave 0) ----
        if (wave == 0){
            f32v4 accF = {0.f, 0.f, 0.f, 0.f};
            int g8 = col & 7;
#pragma unroll
            for (int ks = 0; ks < 24; ks++){
                s16v8 a = *(const s16v8*)&bufX[g8 * 1008 + ks * 32 + quad * 8];
                s16v8 bfr = {0, 0, 0, 0, 0, 0, 0, 0};
                if (col < 12)
                    bfr = *(const s16v8*)(fw + (size_t)col * 768 + ks * 32 + quad * 8);
                accF = __builtin_amdgcn_mfma_f32_16x16x32_bf16(a, bfr, accF, 0, 0, 0);
            }
            if (col < 12){
                float bb = bf2f(fb[col]);
#pragma unroll
                for (int r = 0; r < 4; r++){
                    int g = quad * 4 + r;
                    if (g < 8) outFin[(size_t)(n0 + g) * 12 + col] = accF[r] + bb;
                }
            }
        }
    }
}

// ---------------- launch ----------------
static inline size_t align256(size_t x){ return (x + 255) & ~(size_t)255; }

extern "C" void kernel_launch(void* const* d_in, const int* in_sizes, int n_in,
                              void* d_out, int out_size, void* d_ws, size_t ws_size,
                              hipStream_t stream){
    const float* x  = (const float*)d_in[0];
    const int* ei   = (const int*)d_in[1];
    const float* ew = (const float*)d_in[2];

    char* w = (char*)d_ws;
    u16* bufA    = (u16*)w;  w += align256((size_t)N_NODES * 768 * sizeof(u16));
    u16* bufB    = (u16*)w;  w += align256((size_t)N_NODES * 768 * sizeof(u16));
    float* deg   = (float*)w; w += align256(N_NODES * sizeof(float));
    float* dis   = (float*)w; w += align256(N_NODES * sizeof(float));
    int* cnt     = (int*)w;   w += align256(N_NODES * sizeof(int));
    int* off     = (int*)w;   w += align256((N_NODES + 1) * sizeof(int));
    int* cur     = (int*)w;   w += align256(N_NODES * sizeof(int));
    int2* epack  = (int2*)w;  w += align256((size_t)N_EDGES * sizeof(int2));
    u16* cvt     = (u16*)w;   w += align256(104076 * sizeof(u16));

    u16* tc1a_w = cvt + 0;        // [d][128][32]
    u16* tc1a_b = cvt + 12288;
    u16* gc1_w  = cvt + 12416;
    u16* gc1_b  = cvt + 16512;
    u16* tc1b_w = cvt + 16576;    // [d][128][64]
    u16* tc1b_b = cvt + 41152;
    u16* tc2a_w = cvt + 41280;    // [d][128][64]
    u16* tc2a_b = cvt + 65856;
    u16* gc2_w  = cvt + 65984;
    u16* gc2_b  = cvt + 70080;
    u16* tc2b_w = cvt + 70144;    // [d][128][64]
    u16* tc2b_b = cvt + 94720;
    u16* fin_w  = cvt + 94848;
    u16* fin_b  = cvt + 104064;

    SmallPtrs ps;
    ps.p[0]  = d_in[3];  ps.p[1]  = d_in[4];
    ps.p[2]  = d_in[5];  ps.p[3]  = d_in[6];
    ps.p[4]  = d_in[7];  ps.p[5]  = d_in[8];
    ps.p[6]  = d_in[9];  ps.p[7]  = d_in[10];
    ps.p[8]  = d_in[11]; ps.p[9]  = d_in[12];
    ps.p[10] = d_in[13]; ps.p[11] = d_in[14];
    ps.p[12] = d_in[15]; ps.p[13] = d_in[16];

    k_convert_init<<<(104076 + 255) / 256, 256, 0, stream>>>(ps, cvt, deg, cnt, cur);
    k_gconv_count<<<1250 + 625, 256, 0, stream>>>(x, tc1a_w, tc1a_b, bufA, ei, ew, deg, cnt);
    k_scan_dis<<<1, 1024, 0, stream>>>(cnt, off, deg, dis);
    k_scatter<<<625, 256, 0, stream>>>(ei, ew, dis, off, cur, epack);

    k_fused<false><<<1250, 256, 0, stream>>>(bufA, dis, off, epack,
                                             gc1_w, gc1_b, tc1b_w, tc1b_b,
                                             tc2a_w, tc2a_b, nullptr, nullptr,
                                             bufB, nullptr);
    k_fused<true><<<1250, 256, 0, stream>>>(bufB, dis, off, epack,
                                            gc2_w, gc2_b, tc2b_w, tc2b_b,
                                            nullptr, nullptr, fin_w, fin_b,
                                            nullptr, (float*)d_out);
}

// Round 7
// 254.550 us; speedup vs baseline: 2.9389x; 1.0474x over previous
//
#include <hip/hip_runtime.h>
#include <hip/hip_bf16.h>
#include <stdint.h>

#define N_NODES 10000
#define N_EDGES 160000

typedef unsigned short u16;
typedef unsigned int u32;
typedef short s16v8 __attribute__((ext_vector_type(8)));
typedef float f32v4 __attribute__((ext_vector_type(4)));

__device__ __forceinline__ float bf2f(u16 v){ return __uint_as_float(((u32)v) << 16); }
__device__ __forceinline__ u16 f2bf(float f){
    u32 u = __float_as_uint(f);
    u32 r = (u + 0x7fffu + ((u >> 16) & 1u)) >> 16;
    return (u16)r;
}

// ---------------- weights fp32->bf16 (+tconv transpose to [d][o][c]) + graph init ----------------
struct SmallPtrs { const void* p[14]; };

__device__ __constant__ const int g_seg_off[15] = {
    0, 12288, 12416, 16512, 16576, 41152, 41280,
    65856, 65984, 70080, 70144, 94720, 94848, 104064, 104076
};
// 0=straight, 1=tconv CIN=32 transpose, 2=tconv CIN=64 transpose
__device__ __constant__ const int g_seg_kind[14] = {
    1, 0, 0, 0, 2, 0, 2, 0, 0, 0, 2, 0, 0, 0
};

__global__ void k_convert_init(SmallPtrs ps, u16* __restrict__ dst,
                               float* deg, int* cnt, int* cur){
    int i = blockIdx.x * blockDim.x + threadIdx.x;
    if (i < 104076){
        int seg = 0, base = 0;
#pragma unroll
        for (int s = 0; s < 14; s++){
            if (i >= g_seg_off[s]){ seg = s; base = g_seg_off[s]; }
        }
        int li = i - base;
        float v = ((const float*)ps.p[seg])[li];
        int kind = g_seg_kind[seg];
        int dsto = li;
        if (kind){
            int CIN = (kind == 1) ? 32 : 64;
            int o = li / (3 * CIN);
            int rem = li - o * (3 * CIN);
            int c = rem / 3, d = rem - c * 3;
            dsto = d * 128 * CIN + o * CIN + c;     // [d][o][c]
        }
        dst[base + dsto] = f2bf(v);
    }
    if (i < N_NODES){ deg[i] = 1.0f; cnt[i] = 0; cur[i] = 0; }
}

// ---------------- merged: gconv32 (blocks 0..1249) || edge count (blocks 1250..1874) ----------------
__launch_bounds__(256, 2)
__global__ void k_gconv_count(const float* __restrict__ xin, const u16* __restrict__ wg,
                              const u16* __restrict__ bg, u16* __restrict__ out,
                              const int* __restrict__ ei, const float* __restrict__ ew,
                              float* deg, int* cnt){
    if (blockIdx.x >= 1250){
        int e = (blockIdx.x - 1250) * 256 + threadIdx.x;
        if (e < N_EDGES){
            int d = ei[N_EDGES + e];
            atomicAdd(&deg[d], ew[e]);
            atomicAdd(&cnt[d], 1);
        }
        return;
    }
    __shared__ __attribute__((aligned(16))) u16 xT[8][14][40];
    __shared__ __attribute__((aligned(16))) u16 Ho[8][12][72];
    int tid = threadIdx.x;
    int n0 = blockIdx.x * 8;

    for (int i = tid; i < 8 * 40; i += 256){
        int g = i / 40, c = i % 40;
        xT[g][0][c] = 0; xT[g][13][c] = 0;
    }
    {
        int g = tid >> 5, c = tid & 31;
        const float4* p = (const float4*)(xin + ((size_t)(n0 + g) * 32 + c) * 12);
        float4 v0 = p[0], v1 = p[1], v2 = p[2];
        xT[g][1][c] = f2bf(v0.x);  xT[g][2][c] = f2bf(v0.y);
        xT[g][3][c] = f2bf(v0.z);  xT[g][4][c] = f2bf(v0.w);
        xT[g][5][c] = f2bf(v1.x);  xT[g][6][c] = f2bf(v1.y);
        xT[g][7][c] = f2bf(v1.z);  xT[g][8][c] = f2bf(v1.w);
        xT[g][9][c] = f2bf(v2.x);  xT[g][10][c] = f2bf(v2.y);
        xT[g][11][c] = f2bf(v2.z); xT[g][12][c] = f2bf(v2.w);
    }
    int lane = tid & 63, wave = tid >> 6;
    int col = lane & 15, quad = lane >> 4;
    int o_p = wave * 16 + col, o_q = o_p + 64;

    s16v8 Bf[3][2];
#pragma unroll
    for (int pq = 0; pq < 2; pq++){
        int o = pq ? o_q : o_p;
#pragma unroll
        for (int d = 0; d < 3; d++)
            Bf[d][pq] = *(const s16v8*)(wg + d * 4096 + o * 32 + quad * 8);
    }
    __syncthreads();

    f32v4 aP[6], aQ[6];
#pragma unroll
    for (int mt = 0; mt < 6; mt++){ aP[mt] = (f32v4)0.f; aQ[mt] = (f32v4)0.f; }
#pragma unroll
    for (int mt = 0; mt < 6; mt++){
        int m = mt * 16 + col;
        int g = m / 12, t = m - 12 * g;
#pragma unroll
        for (int d = 0; d < 3; d++){
            s16v8 a = *(const s16v8*)&xT[g][t + d][quad * 8];
            aP[mt] = __builtin_amdgcn_mfma_f32_16x16x32_bf16(a, Bf[d][0], aP[mt], 0, 0, 0);
            aQ[mt] = __builtin_amdgcn_mfma_f32_16x16x32_bf16(a, Bf[d][1], aQ[mt], 0, 0, 0);
        }
    }
    float bP = bf2f(bg[o_p]), bQ = bf2f(bg[o_q]);
#pragma unroll
    for (int mt = 0; mt < 6; mt++){
#pragma unroll
        for (int r = 0; r < 4; r++){
            int m2 = mt * 16 + quad * 4 + r;
            int g = m2 / 12, t = m2 - 12 * g;
            float pv = aP[mt][r] + bP, qv = aQ[mt][r] + bQ;
            Ho[g][t][o_p] = f2bf(pv / (1.f + __expf(-qv)));
        }
    }
    __syncthreads();
    for (int i = tid; i < 768; i += 256){
        int g = i / 96, r = i % 96, t = r / 8, ch = r % 8;
        *(s16v8*)(out + (size_t)(n0 + g) * 768 + t * 64 + ch * 8) = *(const s16v8*)&Ho[g][t][ch * 8];
    }
}

// single-pass scan (shuffle-based) + dis, one block of 1024
__global__ void k_scan_dis(const int* __restrict__ cnt, int* __restrict__ off,
                           const float* __restrict__ deg, float* __restrict__ dis){
    __shared__ int wsum[16], woff[16];
    int t = threadIdx.x;
    int lane = t & 63, wv = t >> 6;
    int base = t * 10;
    int loc[10];
    int mysum = 0;
    if (base < N_NODES){
#pragma unroll
        for (int j = 0; j < 10; j++){ loc[j] = mysum; mysum += cnt[base + j]; }
    }
    int s = mysum;
#pragma unroll
    for (int d = 1; d < 64; d <<= 1){
        int v = __shfl_up(s, d, 64);
        if (lane >= d) s += v;
    }
    if (lane == 63) wsum[wv] = s;
    __syncthreads();
    if (t < 16){
        int v = wsum[t];
        int sc = v;
#pragma unroll
        for (int d = 1; d < 16; d <<= 1){
            int u = __shfl_up(sc, d, 16);
            if (t >= d) sc += u;
        }
        woff[t] = sc - v;
        if (t == 15) off[N_NODES] = sc;
    }
    __syncthreads();
    int tbase = woff[wv] + (s - mysum);
    if (base < N_NODES){
#pragma unroll
        for (int j = 0; j < 10; j++) off[base + j] = tbase + loc[j];
    }
    for (int i = t; i < N_NODES; i += 1024) dis[i] = rsqrtf(deg[i]);
}

__global__ void k_scatter(const int* __restrict__ ei, const float* __restrict__ ew,
                          const float* __restrict__ dis, const int* __restrict__ off,
                          int* cur, int2* __restrict__ epack){
    int e = blockIdx.x * blockDim.x + threadIdx.x;
    if (e < N_EDGES){
        int s = ei[e];
        int d = ei[N_EDGES + e];
        float nw = dis[s] * ew[e] * dis[d];
        int p = off[d] + atomicAdd(&cur[d], 1);
        epack[p] = make_int2(s, __float_as_int(nw));
    }
}

// ---------------- fused: [gather-agg] -> mix(relu) -> gconv w1 -> (MID: gconv w2 | LAST: final) ----------------
// 4 nodes/block, 1 wave per node for the gather.
#define XIDX(g, row, c) (((g) * 14 + (row)) * 72 + (c))

template<bool LAST>
__launch_bounds__(256, 6)
__global__ void k_fused(const u16* __restrict__ src,    // [n][t*64+c] bf16
                        const float* __restrict__ dis, const int* __restrict__ off,
                        const int2* __restrict__ ep,
                        const u16* __restrict__ Wmix, const u16* __restrict__ bmix,
                        const u16* __restrict__ w1, const u16* __restrict__ b1,
                        const u16* __restrict__ w2, const u16* __restrict__ b2,
                        const u16* __restrict__ fw, const u16* __restrict__ fb,
                        u16* __restrict__ outMid, float* __restrict__ outFin){
    __shared__ __attribute__((aligned(16))) u16 bufX[4 * 14 * 72];
    __shared__ __attribute__((aligned(16))) u16 bufY[4 * 14 * 72];
    int tid = threadIdx.x;
    int n0 = blockIdx.x * 4;
    int lane = tid & 63, wave = tid >> 6;
    int col = lane & 15, quad = lane >> 4;

    // zero time-pad rows
    for (int i = tid; i < 4 * 72; i += 256){
        int g = i / 72, c = i % 72;
        bufX[XIDX(g, 0, c)] = 0; bufX[XIDX(g, 13, c)] = 0;
        bufY[XIDX(g, 0, c)] = 0; bufY[XIDX(g, 13, c)] = 0;
    }

    // ---- fused GCN aggregation: one wave per node; lane owns 3x4-elem chunks (flat = lane*4 + i*256) ----
    {
        int g = wave, j = lane;
        int n = n0 + g;
        float dv = dis[n];
        float sw = dv * dv;
        int j4 = j * 4;
        const u16* xr = src + (size_t)n * 768 + j4;
        float acc[12];
#pragma unroll
        for (int i = 0; i < 3; i++){
            ushort4 v = *(const ushort4*)(xr + i * 256);
            acc[i * 4 + 0] = sw * bf2f(v.x);
            acc[i * 4 + 1] = sw * bf2f(v.y);
            acc[i * 4 + 2] = sw * bf2f(v.z);
            acc[i * 4 + 3] = sw * bf2f(v.w);
        }
        int b = off[n], e = off[n + 1];
        int p = b;
        for (; p + 1 < e; p += 2){
            int2 e0 = ep[p], e1 = ep[p + 1];
            float w0 = __int_as_float(e0.y), w1v = __int_as_float(e1.y);
            const u16* q0 = src + (size_t)e0.x * 768 + j4;
            const u16* q1 = src + (size_t)e1.x * 768 + j4;
            ushort4 a0 = *(const ushort4*)(q0);
            ushort4 a1 = *(const ushort4*)(q0 + 256);
            ushort4 a2 = *(const ushort4*)(q0 + 512);
            ushort4 c0 = *(const ushort4*)(q1);
            ushort4 c1 = *(const ushort4*)(q1 + 256);
            ushort4 c2 = *(const ushort4*)(q1 + 512);
            acc[0] = fmaf(w0, bf2f(a0.x), acc[0]); acc[1] = fmaf(w0, bf2f(a0.y), acc[1]);
            acc[2] = fmaf(w0, bf2f(a0.z), acc[2]); acc[3] = fmaf(w0, bf2f(a0.w), acc[3]);
            acc[4] = fmaf(w0, bf2f(a1.x), acc[4]); acc[5] = fmaf(w0, bf2f(a1.y), acc[5]);
            acc[6] = fmaf(w0, bf2f(a1.z), acc[6]); acc[7] = fmaf(w0, bf2f(a1.w), acc[7]);
            acc[8] = fmaf(w0, bf2f(a2.x), acc[8]); acc[9] = fmaf(w0, bf2f(a2.y), acc[9]);
            acc[10] = fmaf(w0, bf2f(a2.z), acc[10]); acc[11] = fmaf(w0, bf2f(a2.w), acc[11]);
            acc[0] = fmaf(w1v, bf2f(c0.x), acc[0]); acc[1] = fmaf(w1v, bf2f(c0.y), acc[1]);
            acc[2] = fmaf(w1v, bf2f(c0.z), acc[2]); acc[3] = fmaf(w1v, bf2f(c0.w), acc[3]);
            acc[4] = fmaf(w1v, bf2f(c1.x), acc[4]); acc[5] = fmaf(w1v, bf2f(c1.y), acc[5]);
            acc[6] = fmaf(w1v, bf2f(c1.z), acc[6]); acc[7] = fmaf(w1v, bf2f(c1.w), acc[7]);
            acc[8] = fmaf(w1v, bf2f(c2.x), acc[8]); acc[9] = fmaf(w1v, bf2f(c2.y), acc[9]);
            acc[10] = fmaf(w1v, bf2f(c2.z), acc[10]); acc[11] = fmaf(w1v, bf2f(c2.w), acc[11]);
        }
        if (p < e){
            int2 e0 = ep[p];
            float w0 = __int_as_float(e0.y);
            const u16* q0 = src + (size_t)e0.x * 768 + j4;
#pragma unroll
            for (int i = 0; i < 3; i++){
                ushort4 v = *(const ushort4*)(q0 + i * 256);
                acc[i * 4 + 0] = fmaf(w0, bf2f(v.x), acc[i * 4 + 0]);
                acc[i * 4 + 1] = fmaf(w0, bf2f(v.y), acc[i * 4 + 1]);
                acc[i * 4 + 2] = fmaf(w0, bf2f(v.z), acc[i * 4 + 2]);
                acc[i * 4 + 3] = fmaf(w0, bf2f(v.w), acc[i * 4 + 3]);
            }
        }
        int t0 = j >> 4, c = j4 & 63;
#pragma unroll
        for (int i = 0; i < 3; i++){
            int t = t0 + i * 4;
            ushort4 hv;
            hv.x = f2bf(acc[i * 4 + 0]); hv.y = f2bf(acc[i * 4 + 1]);
            hv.z = f2bf(acc[i * 4 + 2]); hv.w = f2bf(acc[i * 4 + 3]);
            *(ushort4*)&bufX[XIDX(g, 1 + t, c)] = hv;
        }
    }

    // ---- mix B frags ----
    int o_mix = wave * 16 + col;
    s16v8 Bm[2];
#pragma unroll
    for (int ks = 0; ks < 2; ks++)
        Bm[ks] = *(const s16v8*)(Wmix + (size_t)o_mix * 64 + ks * 32 + quad * 8);
    __syncthreads();

    // ---- mix MFMA: y = relu(z*W + b) ----
    {
        f32v4 accm[3];
#pragma unroll
        for (int mt = 0; mt < 3; mt++) accm[mt] = (f32v4)0.f;
#pragma unroll
        for (int mt = 0; mt < 3; mt++){
            int m = mt * 16 + col;
            int g = m / 12, t = m - 12 * g;
#pragma unroll
            for (int ks = 0; ks < 2; ks++){
                s16v8 a = *(const s16v8*)&bufX[XIDX(g, 1 + t, ks * 32 + quad * 8)];
                accm[mt] = __builtin_amdgcn_mfma_f32_16x16x32_bf16(a, Bm[ks], accm[mt], 0, 0, 0);
            }
        }
        float bm = bf2f(bmix[o_mix]);
#pragma unroll
        for (int mt = 0; mt < 3; mt++){
#pragma unroll
            for (int r = 0; r < 4; r++){
                int m2 = mt * 16 + quad * 4 + r;
                int g = m2 / 12, t = m2 - 12 * g;
                bufY[XIDX(g, 1 + t, o_mix)] = f2bf(fmaxf(accm[mt][r] + bm, 0.f));
            }
        }
    }
    __syncthreads();

    // ---- gated conv 1: bufY -> bufX ----
    {
        int o_p = wave * 16 + col, o_q = o_p + 64;
        s16v8 Bf[3][2][2];
#pragma unroll
        for (int pq = 0; pq < 2; pq++){
            int o = pq ? o_q : o_p;
#pragma unroll
            for (int d = 0; d < 3; d++)
#pragma unroll
                for (int ks = 0; ks < 2; ks++)
                    Bf[d][ks][pq] = *(const s16v8*)(w1 + d * 8192 + o * 64 + ks * 32 + quad * 8);
        }
        f32v4 aP[3], aQ[3];
#pragma unroll
        for (int mt = 0; mt < 3; mt++){ aP[mt] = (f32v4)0.f; aQ[mt] = (f32v4)0.f; }
#pragma unroll
        for (int mt = 0; mt < 3; mt++){
            int m = mt * 16 + col;
            int g = m / 12, t = m - 12 * g;
#pragma unroll
            for (int d = 0; d < 3; d++)
#pragma unroll
                for (int ks = 0; ks < 2; ks++){
                    s16v8 a = *(const s16v8*)&bufY[XIDX(g, t + d, ks * 32 + quad * 8)];
                    aP[mt] = __builtin_amdgcn_mfma_f32_16x16x32_bf16(a, Bf[d][ks][0], aP[mt], 0, 0, 0);
                    aQ[mt] = __builtin_amdgcn_mfma_f32_16x16x32_bf16(a, Bf[d][ks][1], aQ[mt], 0, 0, 0);
                }
        }
        float bP = bf2f(b1[o_p]), bQ = bf2f(b1[o_q]);
#pragma unroll
        for (int mt = 0; mt < 3; mt++){
#pragma unroll
            for (int r = 0; r < 4; r++){
                int m2 = mt * 16 + quad * 4 + r;
                int g = m2 / 12, t = m2 - 12 * g;
                float pv = aP[mt][r] + bP, qv = aQ[mt][r] + bQ;
                u16 hv = f2bf(pv / (1.f + __expf(-qv)));
                if (LAST) bufX[g * 1008 + o_p * 12 + t] = hv;   // H2[g][c*12+t]
                else      bufX[XIDX(g, 1 + t, o_p)] = hv;
            }
        }
    }
    __syncthreads();

    if (!LAST){
        // ---- gated conv 2: bufX -> bufY -> outMid ----
        int o_p = wave * 16 + col, o_q = o_p + 64;
        s16v8 Bf[3][2][2];
#pragma unroll
        for (int pq = 0; pq < 2; pq++){
            int o = pq ? o_q : o_p;
#pragma unroll
            for (int d = 0; d < 3; d++)
#pragma unroll
                for (int ks = 0; ks < 2; ks++)
                    Bf[d][ks][pq] = *(const s16v8*)(w2 + d * 8192 + o * 64 + ks * 32 + quad * 8);
        }
        f32v4 aP[3], aQ[3];
#pragma unroll
        for (int mt = 0; mt < 3; mt++){ aP[mt] = (f32v4)0.f; aQ[mt] = (f32v4)0.f; }
#pragma unroll
        for (int mt = 0; mt < 3; mt++){
            int m = mt * 16 + col;
            int g = m / 12, t = m - 12 * g;
#pragma unroll
            for (int d = 0; d < 3; d++)
#pragma unroll
                for (int ks = 0; ks < 2; ks++){
                    s16v8 a = *(const s16v8*)&bufX[XIDX(g, t + d, ks * 32 + quad * 8)];
                    aP[mt] = __builtin_amdgcn_mfma_f32_16x16x32_bf16(a, Bf[d][ks][0], aP[mt], 0, 0, 0);
                    aQ[mt] = __builtin_amdgcn_mfma_f32_16x16x32_bf16(a, Bf[d][ks][1], aQ[mt], 0, 0, 0);
                }
        }
        float bP = bf2f(b2[o_p]), bQ = bf2f(b2[o_q]);
#pragma unroll
        for (int mt = 0; mt < 3; mt++){
#pragma unroll
            for (int r = 0; r < 4; r++){
                int m2 = mt * 16 + quad * 4 + r;
                int g = m2 / 12, t = m2 - 12 * g;
                float pv = aP[mt][r] + bP, qv = aQ[mt][r] + bQ;
                bufY[XIDX(g, 1 + t, o_p)] = f2bf(pv / (1.f + __expf(-qv)));
            }
        }
        __syncthreads();
        for (int i = tid; i < 384; i += 256){
            int g = i / 96, r = i % 96, t = r / 8, ch = r % 8;
            *(s16v8*)(outMid + (size_t)(n0 + g) * 768 + t * 64 + ch * 8) =
                *(const s16v8*)&bufY[XIDX(g, 1 + t, ch * 8)];
        }
    } else {
        // ---- final: out[g][o] = sum_k H2[g][k]*fw[o][k] + fb[o] (wave 0) ----
        if (wave == 0){
            f32v4 accF = {0.f, 0.f, 0.f, 0.f};
            int g4 = col & 3;
#pragma unroll
            for (int ks = 0; ks < 24; ks++){
                s16v8 a = *(const s16v8*)&bufX[g4 * 1008 + ks * 32 + quad * 8];
                s16v8 bfr = {0, 0, 0, 0, 0, 0, 0, 0};
                if (col < 12)
                    bfr = *(const s16v8*)(fw + (size_t)col * 768 + ks * 32 + quad * 8);
                accF = __builtin_amdgcn_mfma_f32_16x16x32_bf16(a, bfr, accF, 0, 0, 0);
            }
            if (col < 12 && quad == 0){
                float bb = bf2f(fb[col]);
#pragma unroll
                for (int r = 0; r < 4; r++){
                    int g = r;
                    outFin[(size_t)(n0 + g) * 12 + col] = accF[r] + bb;
                }
            }
        }
    }
}

// ---------------- launch ----------------
static inline size_t align256(size_t x){ return (x + 255) & ~(size_t)255; }

extern "C" void kernel_launch(void* const* d_in, const int* in_sizes, int n_in,
                              void* d_out, int out_size, void* d_ws, size_t ws_size,
                              hipStream_t stream){
    const float* x  = (const float*)d_in[0];
    const int* ei   = (const int*)d_in[1];
    const float* ew = (const float*)d_in[2];

    char* w = (char*)d_ws;
    u16* bufA    = (u16*)w;  w += align256((size_t)N_NODES * 768 * sizeof(u16));
    u16* bufB    = (u16*)w;  w += align256((size_t)N_NODES * 768 * sizeof(u16));
    float* deg   = (float*)w; w += align256(N_NODES * sizeof(float));
    float* dis   = (float*)w; w += align256(N_NODES * sizeof(float));
    int* cnt     = (int*)w;   w += align256(N_NODES * sizeof(int));
    int* off     = (int*)w;   w += align256((N_NODES + 1) * sizeof(int));
    int* cur     = (int*)w;   w += align256(N_NODES * sizeof(int));
    int2* epack  = (int2*)w;  w += align256((size_t)N_EDGES * sizeof(int2));
    u16* cvt     = (u16*)w;   w += align256(104076 * sizeof(u16));

    u16* tc1a_w = cvt + 0;        // [d][128][32]
    u16* tc1a_b = cvt + 12288;
    u16* gc1_w  = cvt + 12416;
    u16* gc1_b  = cvt + 16512;
    u16* tc1b_w = cvt + 16576;    // [d][128][64]
    u16* tc1b_b = cvt + 41152;
    u16* tc2a_w = cvt + 41280;    // [d][128][64]
    u16* tc2a_b = cvt + 65856;
    u16* gc2_w  = cvt + 65984;
    u16* gc2_b  = cvt + 70080;
    u16* tc2b_w = cvt + 70144;    // [d][128][64]
    u16* tc2b_b = cvt + 94720;
    u16* fin_w  = cvt + 94848;
    u16* fin_b  = cvt + 104064;

    SmallPtrs ps;
    ps.p[0]  = d_in[3];  ps.p[1]  = d_in[4];
    ps.p[2]  = d_in[5];  ps.p[3]  = d_in[6];
    ps.p[4]  = d_in[7];  ps.p[5]  = d_in[8];
    ps.p[6]  = d_in[9];  ps.p[7]  = d_in[10];
    ps.p[8]  = d_in[11]; ps.p[9]  = d_in[12];
    ps.p[10] = d_in[13]; ps.p[11] = d_in[14];
    ps.p[12] = d_in[15]; ps.p[13] = d_in[16];

    k_convert_init<<<(104076 + 255) / 256, 256, 0, stream>>>(ps, cvt, deg, cnt, cur);
    k_gconv_count<<<1250 + 625, 256, 0, stream>>>(x, tc1a_w, tc1a_b, bufA, ei, ew, deg, cnt);
    k_scan_dis<<<1, 1024, 0, stream>>>(cnt, off, deg, dis);
    k_scatter<<<625, 256, 0, stream>>>(ei, ew, dis, off, cur, epack);

    k_fused<false><<<2500, 256, 0, stream>>>(bufA, dis, off, epack,
                                             gc1_w, gc1_b, tc1b_w, tc1b_b,
                                             tc2a_w, tc2a_b, nullptr, nullptr,
                                             bufB, nullptr);
    k_fused<true><<<2500, 256, 0, stream>>>(bufB, dis, off, epack,
                                            gc2_w, gc2_b, tc2b_w, tc2b_b,
                                            nullptr, nullptr, fin_w, fin_b,
                                            nullptr, (float*)d_out);
}